// Round 15
// baseline (102.868 us; speedup 1.0000x reference)
//
#include <hip/hip_runtime.h>
#include <hip/hip_bf16.h>

#define B_ 2
#define T_ 2048
#define C_ 1024
#define NH_ 16
#define NKV_ 4
#define HD_ 64
#define NQKV_ 1536           // (NH + 2*NKV) * HD
#define M_ 4096              // B_ * T_

typedef __attribute__((ext_vector_type(8))) __bf16 bf16x8;
typedef __attribute__((ext_vector_type(4))) __bf16 bf16x4;
typedef __attribute__((ext_vector_type(4))) short s16x4;
typedef __attribute__((ext_vector_type(4))) float f32x4;
typedef __attribute__((ext_vector_type(4))) unsigned int u32x4;

#if defined(__has_builtin)
#if __has_builtin(__builtin_amdgcn_mfma_f32_16x16x16bf16_1k)
#define MFMA16_OK 1
#endif
#endif
#ifndef MFMA16_OK
#define MFMA16_OK 0
#endif

// raw v_exp_f32 (D = 2^S0): 1 instruction, ~1 ulp — plenty for bf16 outputs.
__device__ __forceinline__ float fast_exp2(float x) { return __builtin_amdgcn_exp2f(x); }

#define GLOAD_LDS16(gptr, lptr)                                                        \
  __builtin_amdgcn_global_load_lds(                                                    \
      (const __attribute__((address_space(1))) unsigned int*)(gptr),                   \
      (__attribute__((address_space(3))) unsigned int*)(lptr), 16, 0, 0)

// ---- shared transpose-tile body: in [K][N] fp32 -> out [N][K] bf16 ----
__device__ __forceinline__ void transpose_tile_body(const float* __restrict__ in,
                                                    __bf16* __restrict__ out,
                                                    int K, int N, int n0, int k0,
                                                    __bf16 (*tile)[72], int tid) {
  const int tr = tid >> 4, tc4 = (tid & 15) << 2;
  #pragma unroll
  for (int p = 0; p < 4; ++p) {
    const int k = k0 + p * 16 + tr;
    const float4 v = *(const float4*)&in[(size_t)k * N + n0 + tc4];
    tile[tc4 + 0][p * 16 + tr] = (__bf16)v.x;
    tile[tc4 + 1][p * 16 + tr] = (__bf16)v.y;
    tile[tc4 + 2][p * 16 + tr] = (__bf16)v.z;
    tile[tc4 + 3][p * 16 + tr] = (__bf16)v.w;
  }
  __syncthreads();
  #pragma unroll
  for (int p = 0; p < 4; ++p) {
    const int n = n0 + p * 16 + tr;
    bf16x4 o;
    o.x = tile[p * 16 + tr][tc4 + 0];
    o.y = tile[p * 16 + tr][tc4 + 1];
    o.z = tile[p * 16 + tr][tc4 + 2];
    o.w = tile[p * 16 + tr][tc4 + 3];
    *(bf16x4*)&out[(size_t)n * K + k0 + tc4] = o;
  }
}

// ---- fused prep: cast_x | T(Wqkv) | T(Wproj) | rope_table ----
#define NB_CASTX 2048
#define NB_TWQKV 384
#define NB_TWPROJ 256
#define PREP_GRID (NB_CASTX + NB_TWQKV + NB_TWPROJ + 256)
__global__ __launch_bounds__(256) void prep_kernel(const float* __restrict__ x,
                                                   const float* __restrict__ Wqkv,
                                                   const float* __restrict__ Wproj,
                                                   __bf16* __restrict__ xb,
                                                   __bf16* __restrict__ wqkvT,
                                                   __bf16* __restrict__ wprojT,
                                                   float* __restrict__ cosT,
                                                   float* __restrict__ sinT) {
  __shared__ __bf16 tile[64][72];
  const int blk = blockIdx.x, tid = threadIdx.x;
  if (blk < NB_CASTX) {                      // cast x: 8 elems/thread
    const int i = blk * 256 + tid;
    const float4 v0 = ((const float4*)x)[2 * i];
    const float4 v1 = ((const float4*)x)[2 * i + 1];
    bf16x8 o;
    o[0] = (__bf16)v0.x; o[1] = (__bf16)v0.y; o[2] = (__bf16)v0.z; o[3] = (__bf16)v0.w;
    o[4] = (__bf16)v1.x; o[5] = (__bf16)v1.y; o[6] = (__bf16)v1.z; o[7] = (__bf16)v1.w;
    ((bf16x8*)xb)[i] = o;
  } else if (blk < NB_CASTX + NB_TWQKV) {    // transpose Wqkv
    const int bx = blk - NB_CASTX;
    transpose_tile_body(Wqkv, wqkvT, C_, NQKV_, (bx % (NQKV_ / 64)) * 64,
                        (bx / (NQKV_ / 64)) * 64, tile, tid);
  } else if (blk < NB_CASTX + NB_TWQKV + NB_TWPROJ) {  // transpose Wproj
    const int bx = blk - NB_CASTX - NB_TWQKV;
    transpose_tile_body(Wproj, wprojT, C_, C_, (bx % (C_ / 64)) * 64,
                        (bx / (C_ / 64)) * 64, tile, tid);
  } else {                                   // RoPE cos/sin tables [T][32]
    const int idx = (blk - NB_CASTX - NB_TWQKV - NB_TWPROJ) * 256 + tid;
    const int t = idx >> 5, i = idx & 31;
    const float inv = powf(10000.0f, -(float)i * (1.0f / 32.0f));
    const float ang = (float)t * inv;
    cosT[idx] = cosf(ang);
    sinT[idx] = sinf(ang);
  }
}

// ---- GEMM1 with FUSED RoPE + scatter epilogue: xb[M][C] * wqkvT[N][K]^T ----
__global__ __launch_bounds__(256) void gemm_qkv_kernel(const __bf16* __restrict__ A,
                                                       const __bf16* __restrict__ Bt,
                                                       const float* __restrict__ cosT,
                                                       const float* __restrict__ sinT,
                                                       __bf16* __restrict__ Q,
                                                       __bf16* __restrict__ Kb,
                                                       __bf16* __restrict__ Vt) {
  const int N = NQKV_, K = C_;
  __shared__ __align__(16) __bf16 lA[2][128 * 64];
  __shared__ __align__(16) __bf16 lB[2][64 * 64];
  const int tid = threadIdx.x;
  const int lane = tid & 63;
  const int wave = tid >> 6;
  const int wr = wave >> 1, wc = wave & 1;
  const int m0 = blockIdx.y * 128, n0 = blockIdx.x * 64;
  const int srow = tid >> 3, kc = tid & 7;
  const int r16 = lane & 15, g = lane >> 4;
  f32x4 acc[4][2] = {};
  const int nt = K >> 6;

#define GSTAGE(buf, k0)                                                                   \
  {                                                                                       \
    _Pragma("unroll")                                                                     \
    for (int p = 0; p < 4; ++p) {                                                         \
      const int row = p * 32 + srow;                                                      \
      const int sw = (kc ^ (row & 7)) * 8;                                                \
      GLOAD_LDS16(&A[(size_t)(m0 + row) * K + (k0) + sw], &lA[buf][row * 64 + kc * 8]);   \
    }                                                                                     \
    _Pragma("unroll")                                                                     \
    for (int p = 0; p < 2; ++p) {                                                         \
      const int row = p * 32 + srow;                                                      \
      const int sw = (kc ^ (row & 7)) * 8;                                                \
      GLOAD_LDS16(&Bt[(size_t)(n0 + row) * K + (k0) + sw], &lB[buf][row * 64 + kc * 8]);  \
    }                                                                                     \
  }
  GSTAGE(0, 0);
  asm volatile("s_waitcnt vmcnt(0)" ::: "memory");
  __syncthreads();
  int cur = 0;
  for (int t = 0; t < nt; ++t) {
    if (t + 1 < nt) GSTAGE(cur ^ 1, (t + 1) << 6);
    #pragma unroll
    for (int ks = 0; ks < 64; ks += 32) {
      bf16x8 af[4], bfr[2];
      const int kch = (ks >> 3) + g;
      #pragma unroll
      for (int mi = 0; mi < 4; ++mi) {
        const int row = wr * 64 + mi * 16 + r16;
        af[mi] = *(const bf16x8*)&lA[cur][row * 64 + (kch ^ (row & 7)) * 8];
      }
      #pragma unroll
      for (int ni = 0; ni < 2; ++ni) {
        const int row = wc * 32 + ni * 16 + r16;
        bfr[ni] = *(const bf16x8*)&lB[cur][row * 64 + (kch ^ (row & 7)) * 8];
      }
      #pragma unroll
      for (int mi = 0; mi < 4; ++mi)
        #pragma unroll
        for (int ni = 0; ni < 2; ++ni)
          acc[mi][ni] = __builtin_amdgcn_mfma_f32_16x16x32_bf16(af[mi], bfr[ni], acc[mi][ni], 0, 0, 0);
    }
    asm volatile("s_waitcnt vmcnt(0)" ::: "memory");
    __syncthreads();
    cur ^= 1;
  }
#undef GSTAGE
  // ---- fused epilogue ----
  const int bx = blockIdx.x;          // head tile: 0..15 Q, 16..19 K, 20..23 V
  const bool isV = bx >= 20;
  const bool isQ = bx < 16;
  const float qs = 0.125f * 1.44269504f;
  const bool evenD = (r16 & 1) == 0;
  #pragma unroll
  for (int mi = 0; mi < 4; ++mi) {
    const int t0g = m0 + wr * 64 + mi * 16 + g * 4;  // 4 consecutive t rows
    const int b = t0g >> 11, tq0 = t0g & 2047;
    #pragma unroll
    for (int ni = 0; ni < 2; ++ni) {
      const int d = wc * 32 + ni * 16 + r16;
      if (isV) {
        const int hv = bx - 20;
        bf16x4 o4;
        #pragma unroll
        for (int j = 0; j < 4; ++j) o4[j] = (__bf16)acc[mi][ni][j];
        *(bf16x4*)&Vt[(((size_t)b * NKV_ + hv) * HD_ + d) * T_ + tq0] = o4;
      } else {
        const int ir = d >> 1;
        #pragma unroll
        for (int j = 0; j < 4; ++j) {
          const float val = acc[mi][ni][j];
          const float oth = __shfl_xor(val, 1);
          const float c = cosT[(tq0 + j) * 32 + ir];
          const float s = sinT[(tq0 + j) * 32 + ir];
          float o = evenD ? (val * c - oth * s) : (oth * s + val * c);
          if (isQ) {
            Q[(((size_t)b * NH_ + bx) * T_ + tq0 + j) * HD_ + d] = (__bf16)(o * qs);
          } else {
            Kb[(((size_t)b * NKV_ + (bx - 16)) * T_ + tq0 + j) * HD_ + d] = (__bf16)o;
          }
        }
      }
    }
  }
}

// ------- bf16 TN GEMM (generic): A[M][K] * Bt[N][K]^T -> C[M][N] fp32 -------
__global__ __launch_bounds__(256) void gemm_tn_kernel(const __bf16* __restrict__ A,
                                                      const __bf16* __restrict__ Bt,
                                                      float* __restrict__ C, int N, int K) {
  __shared__ __align__(16) __bf16 lA[2][128 * 64];
  __shared__ __align__(16) __bf16 lB[2][64 * 64];
  const int tid = threadIdx.x;
  const int lane = tid & 63;
  const int wave = tid >> 6;
  const int wr = wave >> 1, wc = wave & 1;
  const int m0 = blockIdx.y * 128, n0 = blockIdx.x * 64;
  const int srow = tid >> 3, kc = tid & 7;
  const int r16 = lane & 15, g = lane >> 4;
  f32x4 acc[4][2] = {};
  const int nt = K >> 6;

#define GSTAGE(buf, k0)                                                                   \
  {                                                                                       \
    _Pragma("unroll")                                                                     \
    for (int p = 0; p < 4; ++p) {                                                         \
      const int row = p * 32 + srow;                                                      \
      const int sw = (kc ^ (row & 7)) * 8;                                                \
      GLOAD_LDS16(&A[(size_t)(m0 + row) * K + (k0) + sw], &lA[buf][row * 64 + kc * 8]);   \
    }                                                                                     \
    _Pragma("unroll")                                                                     \
    for (int p = 0; p < 2; ++p) {                                                         \
      const int row = p * 32 + srow;                                                      \
      const int sw = (kc ^ (row & 7)) * 8;                                                \
      GLOAD_LDS16(&Bt[(size_t)(n0 + row) * K + (k0) + sw], &lB[buf][row * 64 + kc * 8]);  \
    }                                                                                     \
  }
  GSTAGE(0, 0);
  asm volatile("s_waitcnt vmcnt(0)" ::: "memory");
  __syncthreads();
  int cur = 0;
  for (int t = 0; t < nt; ++t) {
    if (t + 1 < nt) GSTAGE(cur ^ 1, (t + 1) << 6);
    #pragma unroll
    for (int ks = 0; ks < 64; ks += 32) {
      bf16x8 af[4], bfr[2];
      const int kch = (ks >> 3) + g;
      #pragma unroll
      for (int mi = 0; mi < 4; ++mi) {
        const int row = wr * 64 + mi * 16 + r16;
        af[mi] = *(const bf16x8*)&lA[cur][row * 64 + (kch ^ (row & 7)) * 8];
      }
      #pragma unroll
      for (int ni = 0; ni < 2; ++ni) {
        const int row = wc * 32 + ni * 16 + r16;
        bfr[ni] = *(const bf16x8*)&lB[cur][row * 64 + (kch ^ (row & 7)) * 8];
      }
      #pragma unroll
      for (int mi = 0; mi < 4; ++mi)
        #pragma unroll
        for (int ni = 0; ni < 2; ++ni)
          acc[mi][ni] = __builtin_amdgcn_mfma_f32_16x16x32_bf16(af[mi], bfr[ni], acc[mi][ni], 0, 0, 0);
    }
    asm volatile("s_waitcnt vmcnt(0)" ::: "memory");
    __syncthreads();
    cur ^= 1;
  }
  #pragma unroll
  for (int mi = 0; mi < 4; ++mi) {
    const int r0 = m0 + wr * 64 + mi * 16 + g * 4;
    #pragma unroll
    for (int ni = 0; ni < 2; ++ni) {
      const int c = n0 + wc * 32 + ni * 16 + r16;
      #pragma unroll
      for (int j = 0; j < 4; ++j)
        C[(size_t)(r0 + j) * N + c] = acc[mi][ni][j];
    }
  }
#undef GSTAGE
}

// ---- flash attention: triangle-paired, swapped-QK softmax, KVBLK=64 ----
// NEW (MFMA16_OK): PV uses v_mfma_f32_16x16x16_bf16 whose A-frag k-layout
// (k=g*4+j) EXACTLY matches QK's D-layout — P stays in registers. Removes
// the P LDS round-trip (4 ds_write + lgkmcnt(0) full drain + 2 ds_read per
// side) that serialized the chain and caused the 1.08M bank conflicts.
// Fallback (!MFMA16_OK): R14's proven pP path.
__global__ __launch_bounds__(256) void attn_kernel(const __bf16* __restrict__ Q,
                                                   const __bf16* __restrict__ Kb,
                                                   const __bf16* __restrict__ Vt,
                                                   __bf16* __restrict__ Y) {
  __shared__ __align__(16) __bf16 lK[2][64 * 64];   // [kv][d], swizzled
  __shared__ __align__(16) __bf16 lV[2][64 * 64];   // [d][kv], swizzled
#if !MFMA16_OK
  __shared__ __align__(16) __bf16 pP[4][16 * 64];   // per-wave [q][kv], swizzled
#endif
  const int tid = threadIdx.x;
  const int lane = tid & 63, wave = tid >> 6;
  const int r16 = lane & 15, g = lane >> 4;
  // bijective XCD swizzle (T1)
  const int logical = (blockIdx.x & 7) * 64 + (blockIdx.x >> 3);
  const int i = logical & 15;        // pair index: q-tiles {i, 31-i}
  const int bh = logical >> 4;
  const int b = bh >> 4, h = bh & 15;
  const int kvh = h >> 2;  // GQA rep = 4
  const __bf16* Qp = Q + ((size_t)b * NH_ + h) * T_ * HD_;
  const __bf16* Kp = Kb + ((size_t)b * NKV_ + kvh) * T_ * HD_;
  const __bf16* Vp = Vt + ((size_t)b * NKV_ + kvh) * HD_ * T_;
  const int qtile[2] = { i, 31 - i };
  const int srow = tid >> 3, kc = tid & 7;          // staging: 8x16B chunks/row

#define ASTAGE(buf, kv0_)                                                                  \
  {                                                                                        \
    _Pragma("unroll")                                                                      \
    for (int p = 0; p < 2; ++p) {                                                          \
      const int row = p * 32 + srow;                                                       \
      const int sw = (kc ^ (row & 7)) * 8;                                                 \
      GLOAD_LDS16(&Kp[(size_t)((kv0_) + row) * HD_ + sw], &lK[buf][row * 64 + kc * 8]);    \
      GLOAD_LDS16(&Vp[(size_t)row * T_ + (kv0_) + sw], &lV[buf][row * 64 + kc * 8]);       \
    }                                                                                      \
  }

  // Q fragments; pre-scaled by 1/8*log2e in gemm_qkv epilogue.
  bf16x8 qf[2][2];
  #pragma unroll
  for (int sd = 0; sd < 2; ++sd)
    #pragma unroll
    for (int c = 0; c < 2; ++c)
      qf[sd][c] = *(const bf16x8*)&Qp[(size_t)(qtile[sd] * 64 + wave * 16 + r16) * HD_ + (c * 4 + g) * 8];

  f32x4 o[2][4] = {};
  float mS[2], lS[2];
  #pragma unroll
  for (int sd = 0; sd < 2; ++sd) { mS[sd] = -__builtin_inff(); lS[sd] = 0.0f; }

  const int ntiles = 32 - i;         // KV tiles needed by side B (q-tile 31-i)
  ASTAGE(0, 0);
  asm volatile("s_waitcnt vmcnt(0)" ::: "memory");
  __syncthreads();
  int cur = 0;

  for (int t = 0; t < ntiles; ++t) {
    const int kv0 = t << 6;
    if (t + 1 < ntiles) ASTAGE(cur ^ 1, kv0 + 64);  // next tile under compute

    // ---- hoisted K fragment reads (b128), shared by both sides ----
    bf16x8 kf[2][4];
    #pragma unroll
    for (int c = 0; c < 2; ++c)
      #pragma unroll
      for (int ni = 0; ni < 4; ++ni) {
        const int row = ni * 16 + r16;
        kf[c][ni] = *(const bf16x8*)&lK[cur][row * 64 + ((c * 4 + g) ^ (row & 7)) * 8];
      }
#if MFMA16_OK
    // ---- hoisted V fragments for K=16 PV: [s][nf], 8B each, shared ----
    // B-frag (16x16x16): col=r16 -> d=nf*16+r16; k=g*4+j -> kv=s*16+g*4+j.
    s16x4 vf2[4][4];
    #pragma unroll
    for (int s = 0; s < 4; ++s)
      #pragma unroll
      for (int nf = 0; nf < 4; ++nf) {
        const int row = nf * 16 + r16;
        vf2[s][nf] = *(const s16x4*)&lV[cur][row * 64 + (((2 * s + (g >> 1)) ^ (row & 7)) * 8) + (g & 1) * 4];
      }
#else
    bf16x8 vf[2][4];
    #pragma unroll
    for (int c = 0; c < 2; ++c)
      #pragma unroll
      for (int ni = 0; ni < 4; ++ni) {
        const int row = ni * 16 + r16;
        vf[c][ni] = *(const bf16x8*)&lV[cur][row * 64 + ((c * 4 + g) ^ (row & 7)) * 8];
      }
#endif

    #pragma unroll
    for (int sd = 0; sd < 2; ++sd) {
      if (sd == 0 && t > i) continue;       // side A inactive past its diagonal
      const int qw = qtile[sd] * 64 + wave * 16;

      // ---- QK^T swapped: s[ni][j] = S[kv0+ni*16+g*4+j][qw+r16] ----
      f32x4 s[4] = {};
      #pragma unroll
      for (int c = 0; c < 2; ++c)
        #pragma unroll
        for (int ni = 0; ni < 4; ++ni)
          s[ni] = __builtin_amdgcn_mfma_f32_16x16x32_bf16(kf[c][ni], qf[sd][c], s[ni], 0, 0, 0);

      // ---- causal mask (diagonal tile of this side only) ----
      if (t == ((sd == 0) ? i : (ntiles - 1))) {
        #pragma unroll
        for (int ni = 0; ni < 4; ++ni)
          #pragma unroll
          for (int j = 0; j < 4; ++j)
            if (kv0 + ni * 16 + g * 4 + j > qw + r16) s[ni][j] = -__builtin_inff();
      }

      // ---- softmax (lane owns full row q=qw+r16 of S^T) ----
      float t0 = fmaxf(fmaxf(s[0][0], s[0][1]), s[0][2]);
      float t1 = fmaxf(fmaxf(s[0][3], s[1][0]), s[1][1]);
      float t2 = fmaxf(fmaxf(s[1][2], s[1][3]), s[2][0]);
      float t3 = fmaxf(fmaxf(s[2][1], s[2][2]), s[2][3]);
      float t4 = fmaxf(fmaxf(s[3][0], s[3][1]), s[3][2]);
      float pm = fmaxf(fmaxf(t0, t1), t2);
      pm = fmaxf(pm, fmaxf(t3, t4));
      pm = fmaxf(pm, s[3][3]);
      pm = fmaxf(pm, __shfl_xor(pm, 16));
      pm = fmaxf(pm, __shfl_xor(pm, 32));
      const bool upd = pm > mS[sd] + 8.0f;   // deferred-max (T13)
      const float nm = upd ? pm : mS[sd];
      const float sc = fast_exp2(mS[sd] - nm);   // ==1.0 exactly when !upd
      mS[sd] = nm;
      lS[sd] *= sc;
      if (__any(upd)) {  // redistribute sc from q=r16 layout to (g,j) layout
        #pragma unroll
        for (int j = 0; j < 4; ++j) {
          const float scj = __shfl(sc, g * 4 + j);
          #pragma unroll
          for (int nf = 0; nf < 4; ++nf) o[sd][nf][j] *= scj;
        }
      }
      float rs = 0.0f;
#if MFMA16_OK
      // ---- P stays in registers: pf4[s] is the K=16 A-frag directly ----
      bf16x4 pf4[4];
      #pragma unroll
      for (int ni = 0; ni < 4; ++ni)
        #pragma unroll
        for (int j = 0; j < 4; ++j) {
          const float pv = fast_exp2(s[ni][j] - mS[sd]);
          rs += pv;
          pf4[ni][j] = (__bf16)pv;
        }
      rs += __shfl_xor(rs, 16);
      rs += __shfl_xor(rs, 32);
      lS[sd] += rs;
      // ---- PV: O += P * V, 16 K=16 MFMAs, zero LDS/fence ----
      #pragma unroll
      for (int ss = 0; ss < 4; ++ss) {
        const s16x4 pa = __builtin_bit_cast(s16x4, pf4[ss]);
        #pragma unroll
        for (int nf = 0; nf < 4; ++nf)
          o[sd][nf] = __builtin_amdgcn_mfma_f32_16x16x16bf16_1k(pa, vf2[ss][nf], o[sd][nf], 0, 0, 0);
      }
#else
      // ---- fallback: P through swizzled LDS (R14 path) ----
      #pragma unroll
      for (int ni = 0; ni < 4; ++ni) {
        bf16x4 pb;
        #pragma unroll
        for (int j = 0; j < 4; ++j) {
          const float pv = fast_exp2(s[ni][j] - mS[sd]);
          rs += pv;
          pb[j] = (__bf16)pv;
        }
        const int ch = 2 * ni + (g >> 1);
        *(bf16x4*)&pP[wave][r16 * 64 + ((ch ^ (r16 & 7)) * 8) + (g & 1) * 4] = pb;
      }
      rs += __shfl_xor(rs, 16);
      rs += __shfl_xor(rs, 32);
      lS[sd] += rs;
      asm volatile("s_waitcnt lgkmcnt(0)" ::: "memory");
      #pragma unroll
      for (int c = 0; c < 2; ++c) {
        const bf16x8 pf = *(const bf16x8*)&pP[wave][r16 * 64 + (((c * 4 + g) ^ (r16 & 7)) * 8)];
        #pragma unroll
        for (int nf = 0; nf < 4; ++nf)
          o[sd][nf] = __builtin_amdgcn_mfma_f32_16x16x32_bf16(pf, vf[c][nf], o[sd][nf], 0, 0, 0);
      }
#endif
    }

    asm volatile("s_waitcnt vmcnt(0)" ::: "memory");  // next-tile loads landed
    __syncthreads();
    cur ^= 1;
  }

  // ---- epilogue -> Y[b][t][h][d] bf16 (both sides); l via shfl ----
  #pragma unroll
  for (int sd = 0; sd < 2; ++sd) {
    const int qw = qtile[sd] * 64 + wave * 16;
    #pragma unroll
    for (int j = 0; j < 4; ++j) {
      const float lq = __shfl(lS[sd], g * 4 + j);
      const float inv = 1.0f / lq;
      const int tq = qw + g * 4 + j;
      #pragma unroll
      for (int nf = 0; nf < 4; ++nf) {
        const int d = nf * 16 + r16;
        Y[(((size_t)b * T_ + tq) * NH_ + h) * HD_ + d] = (__bf16)(o[sd][nf][j] * inv);
      }
    }
  }
#undef ASTAGE
}

extern "C" void kernel_launch(void* const* d_in, const int* in_sizes, int n_in,
                              void* d_out, int out_size, void* d_ws, size_t ws_size,
                              hipStream_t stream) {
  const float* x = (const float*)d_in[0];
  const float* Wqkv = (const float*)d_in[1];
  const float* Wproj = (const float*)d_in[2];
  float* out = (float*)d_out;

  char* ws = (char*)d_ws;
  size_t off = 0;
  auto alloc = [&](size_t bytes) {
    char* p = ws + off;
    off += (bytes + 255) & ~(size_t)255;
    return p;
  };
  __bf16* xb     = (__bf16*)alloc((size_t)M_ * C_ * 2);          // 8 MB
  __bf16* wqkvT  = (__bf16*)alloc((size_t)NQKV_ * C_ * 2);       // 3 MB
  __bf16* wprojT = (__bf16*)alloc((size_t)C_ * C_ * 2);          // 2 MB
  float*  cosT   = (float*)alloc((size_t)T_ * 32 * 4);
  float*  sinT   = (float*)alloc((size_t)T_ * 32 * 4);
  __bf16* Qb     = (__bf16*)alloc((size_t)B_ * NH_ * T_ * HD_ * 2);
  __bf16* Kb     = (__bf16*)alloc((size_t)B_ * NKV_ * T_ * HD_ * 2);
  __bf16* Vt     = (__bf16*)alloc((size_t)B_ * NKV_ * T_ * HD_ * 2);
  __bf16* Yb     = (__bf16*)alloc((size_t)M_ * C_ * 2);          // 8 MB

  hipLaunchKernelGGL(prep_kernel, dim3(PREP_GRID), dim3(256), 0, stream,
                     x, Wqkv, Wproj, xb, wqkvT, wprojT, cosT, sinT);
  hipLaunchKernelGGL(gemm_qkv_kernel, dim3(NQKV_ / 64, M_ / 128), dim3(256), 0, stream,
                     xb, wqkvT, cosT, sinT, Qb, Kb, Vt);
  hipLaunchKernelGGL(attn_kernel, dim3(16 * B_ * NH_), dim3(256), 0, stream, Qb, Kb, Vt, Yb);
  hipLaunchKernelGGL(gemm_tn_kernel, dim3(C_ / 64, M_ / 128), dim3(256), 0, stream,
                     Yb, wprojT, out, C_, C_);
}

// Round 16
// 95.653 us; speedup vs baseline: 1.0754x; 1.0754x over previous
//
#include <hip/hip_runtime.h>
#include <hip/hip_bf16.h>

#define B_ 2
#define T_ 2048
#define C_ 1024
#define NH_ 16
#define NKV_ 4
#define HD_ 64
#define NQKV_ 1536           // (NH + 2*NKV) * HD
#define M_ 4096              // B_ * T_

typedef __attribute__((ext_vector_type(8))) __bf16 bf16x8;
typedef __attribute__((ext_vector_type(4))) __bf16 bf16x4;
typedef __attribute__((ext_vector_type(4))) float f32x4;
typedef __attribute__((ext_vector_type(4))) unsigned int u32x4;

// raw v_exp_f32 (D = 2^S0): 1 instruction, ~1 ulp — plenty for bf16 outputs.
__device__ __forceinline__ float fast_exp2(float x) { return __builtin_amdgcn_exp2f(x); }

#define GLOAD_LDS16(gptr, lptr)                                                        \
  __builtin_amdgcn_global_load_lds(                                                    \
      (const __attribute__((address_space(1))) unsigned int*)(gptr),                   \
      (__attribute__((address_space(3))) unsigned int*)(lptr), 16, 0, 0)

// ---- shared transpose-tile body: in [K][N] fp32 -> out [N][K] bf16 ----
__device__ __forceinline__ void transpose_tile_body(const float* __restrict__ in,
                                                    __bf16* __restrict__ out,
                                                    int K, int N, int n0, int k0,
                                                    __bf16 (*tile)[72], int tid) {
  const int tr = tid >> 4, tc4 = (tid & 15) << 2;
  #pragma unroll
  for (int p = 0; p < 4; ++p) {
    const int k = k0 + p * 16 + tr;
    const float4 v = *(const float4*)&in[(size_t)k * N + n0 + tc4];
    tile[tc4 + 0][p * 16 + tr] = (__bf16)v.x;
    tile[tc4 + 1][p * 16 + tr] = (__bf16)v.y;
    tile[tc4 + 2][p * 16 + tr] = (__bf16)v.z;
    tile[tc4 + 3][p * 16 + tr] = (__bf16)v.w;
  }
  __syncthreads();
  #pragma unroll
  for (int p = 0; p < 4; ++p) {
    const int n = n0 + p * 16 + tr;
    bf16x4 o;
    o.x = tile[p * 16 + tr][tc4 + 0];
    o.y = tile[p * 16 + tr][tc4 + 1];
    o.z = tile[p * 16 + tr][tc4 + 2];
    o.w = tile[p * 16 + tr][tc4 + 3];
    *(bf16x4*)&out[(size_t)n * K + k0 + tc4] = o;
  }
}

// ---- fused prep: cast_x | T(Wqkv) | T(Wproj) | rope_table ----
#define NB_CASTX 2048
#define NB_TWQKV 384
#define NB_TWPROJ 256
#define PREP_GRID (NB_CASTX + NB_TWQKV + NB_TWPROJ + 256)
__global__ __launch_bounds__(256) void prep_kernel(const float* __restrict__ x,
                                                   const float* __restrict__ Wqkv,
                                                   const float* __restrict__ Wproj,
                                                   __bf16* __restrict__ xb,
                                                   __bf16* __restrict__ wqkvT,
                                                   __bf16* __restrict__ wprojT,
                                                   float* __restrict__ cosT,
                                                   float* __restrict__ sinT) {
  __shared__ __bf16 tile[64][72];
  const int blk = blockIdx.x, tid = threadIdx.x;
  if (blk < NB_CASTX) {                      // cast x: 8 elems/thread
    const int i = blk * 256 + tid;
    const float4 v0 = ((const float4*)x)[2 * i];
    const float4 v1 = ((const float4*)x)[2 * i + 1];
    bf16x8 o;
    o[0] = (__bf16)v0.x; o[1] = (__bf16)v0.y; o[2] = (__bf16)v0.z; o[3] = (__bf16)v0.w;
    o[4] = (__bf16)v1.x; o[5] = (__bf16)v1.y; o[6] = (__bf16)v1.z; o[7] = (__bf16)v1.w;
    ((bf16x8*)xb)[i] = o;
  } else if (blk < NB_CASTX + NB_TWQKV) {    // transpose Wqkv
    const int bx = blk - NB_CASTX;
    transpose_tile_body(Wqkv, wqkvT, C_, NQKV_, (bx % (NQKV_ / 64)) * 64,
                        (bx / (NQKV_ / 64)) * 64, tile, tid);
  } else if (blk < NB_CASTX + NB_TWQKV + NB_TWPROJ) {  // transpose Wproj
    const int bx = blk - NB_CASTX - NB_TWQKV;
    transpose_tile_body(Wproj, wprojT, C_, C_, (bx % (C_ / 64)) * 64,
                        (bx / (C_ / 64)) * 64, tile, tid);
  } else {                                   // RoPE cos/sin tables [T][32]
    const int idx = (blk - NB_CASTX - NB_TWQKV - NB_TWPROJ) * 256 + tid;
    const int t = idx >> 5, i = idx & 31;
    const float inv = powf(10000.0f, -(float)i * (1.0f / 32.0f));
    const float ang = (float)t * inv;
    cosT[idx] = cosf(ang);
    sinT[idx] = sinf(ang);
  }
}

// ---- GEMM1 with FUSED RoPE + scatter epilogue: xb[M][C] * wqkvT[N][K]^T ----
// Each 64-col tile = exactly one head. Epilogue applies RoPE to Q/K cols
// (pair (d, d^1) lives in lanes (r16, r16^1) -> one shfl_xor + fma) and
// writes Q[b][h][t][d], K[b][kvh][t][d], Vt[b][kvh][d][t] directly — no qkv
// intermediate. Q pre-scaled by 1/8*log2(e) (exp2-domain softmax).
__global__ __launch_bounds__(256) void gemm_qkv_kernel(const __bf16* __restrict__ A,
                                                       const __bf16* __restrict__ Bt,
                                                       const float* __restrict__ cosT,
                                                       const float* __restrict__ sinT,
                                                       __bf16* __restrict__ Q,
                                                       __bf16* __restrict__ Kb,
                                                       __bf16* __restrict__ Vt) {
  const int N = NQKV_, K = C_;
  __shared__ __align__(16) __bf16 lA[2][128 * 64];
  __shared__ __align__(16) __bf16 lB[2][64 * 64];
  const int tid = threadIdx.x;
  const int lane = tid & 63;
  const int wave = tid >> 6;
  const int wr = wave >> 1, wc = wave & 1;
  const int m0 = blockIdx.y * 128, n0 = blockIdx.x * 64;
  const int srow = tid >> 3, kc = tid & 7;
  const int r16 = lane & 15, g = lane >> 4;
  f32x4 acc[4][2] = {};
  const int nt = K >> 6;

#define GSTAGE(buf, k0)                                                                   \
  {                                                                                       \
    _Pragma("unroll")                                                                     \
    for (int p = 0; p < 4; ++p) {                                                         \
      const int row = p * 32 + srow;                                                      \
      const int sw = (kc ^ (row & 7)) * 8;                                                \
      GLOAD_LDS16(&A[(size_t)(m0 + row) * K + (k0) + sw], &lA[buf][row * 64 + kc * 8]);   \
    }                                                                                     \
    _Pragma("unroll")                                                                     \
    for (int p = 0; p < 2; ++p) {                                                         \
      const int row = p * 32 + srow;                                                      \
      const int sw = (kc ^ (row & 7)) * 8;                                                \
      GLOAD_LDS16(&Bt[(size_t)(n0 + row) * K + (k0) + sw], &lB[buf][row * 64 + kc * 8]);  \
    }                                                                                     \
  }
  GSTAGE(0, 0);
  asm volatile("s_waitcnt vmcnt(0)" ::: "memory");
  __syncthreads();
  int cur = 0;
  for (int t = 0; t < nt; ++t) {
    if (t + 1 < nt) GSTAGE(cur ^ 1, (t + 1) << 6);
    #pragma unroll
    for (int ks = 0; ks < 64; ks += 32) {
      bf16x8 af[4], bfr[2];
      const int kch = (ks >> 3) + g;
      #pragma unroll
      for (int mi = 0; mi < 4; ++mi) {
        const int row = wr * 64 + mi * 16 + r16;
        af[mi] = *(const bf16x8*)&lA[cur][row * 64 + (kch ^ (row & 7)) * 8];
      }
      #pragma unroll
      for (int ni = 0; ni < 2; ++ni) {
        const int row = wc * 32 + ni * 16 + r16;
        bfr[ni] = *(const bf16x8*)&lB[cur][row * 64 + (kch ^ (row & 7)) * 8];
      }
      #pragma unroll
      for (int mi = 0; mi < 4; ++mi)
        #pragma unroll
        for (int ni = 0; ni < 2; ++ni)
          acc[mi][ni] = __builtin_amdgcn_mfma_f32_16x16x32_bf16(af[mi], bfr[ni], acc[mi][ni], 0, 0, 0);
    }
    asm volatile("s_waitcnt vmcnt(0)" ::: "memory");
    __syncthreads();
    cur ^= 1;
  }
#undef GSTAGE
  // ---- fused epilogue ----
  const int bx = blockIdx.x;          // head tile: 0..15 Q, 16..19 K, 20..23 V
  const bool isV = bx >= 20;
  const bool isQ = bx < 16;
  const float qs = 0.125f * 1.44269504f;
  const bool evenD = (r16 & 1) == 0;
  #pragma unroll
  for (int mi = 0; mi < 4; ++mi) {
    const int t0g = m0 + wr * 64 + mi * 16 + g * 4;  // 4 consecutive t rows
    const int b = t0g >> 11, tq0 = t0g & 2047;
    #pragma unroll
    for (int ni = 0; ni < 2; ++ni) {
      const int d = wc * 32 + ni * 16 + r16;
      if (isV) {
        const int hv = bx - 20;
        bf16x4 o4;
        #pragma unroll
        for (int j = 0; j < 4; ++j) o4[j] = (__bf16)acc[mi][ni][j];
        *(bf16x4*)&Vt[(((size_t)b * NKV_ + hv) * HD_ + d) * T_ + tq0] = o4;
      } else {
        const int ir = d >> 1;
        #pragma unroll
        for (int j = 0; j < 4; ++j) {
          const float val = acc[mi][ni][j];
          const float oth = __shfl_xor(val, 1);
          const float c = cosT[(tq0 + j) * 32 + ir];
          const float s = sinT[(tq0 + j) * 32 + ir];
          float o = evenD ? (val * c - oth * s) : (oth * s + val * c);
          if (isQ) {
            Q[(((size_t)b * NH_ + bx) * T_ + tq0 + j) * HD_ + d] = (__bf16)(o * qs);
          } else {
            Kb[(((size_t)b * NKV_ + (bx - 16)) * T_ + tq0 + j) * HD_ + d] = (__bf16)o;
          }
        }
      }
    }
  }
}

// ------- bf16 TN GEMM (generic): A[M][K] * Bt[N][K]^T -> C[M][N] fp32 -------
__global__ __launch_bounds__(256) void gemm_tn_kernel(const __bf16* __restrict__ A,
                                                      const __bf16* __restrict__ Bt,
                                                      float* __restrict__ C, int N, int K) {
  __shared__ __align__(16) __bf16 lA[2][128 * 64];
  __shared__ __align__(16) __bf16 lB[2][64 * 64];
  const int tid = threadIdx.x;
  const int lane = tid & 63;
  const int wave = tid >> 6;
  const int wr = wave >> 1, wc = wave & 1;
  const int m0 = blockIdx.y * 128, n0 = blockIdx.x * 64;
  const int srow = tid >> 3, kc = tid & 7;
  const int r16 = lane & 15, g = lane >> 4;
  f32x4 acc[4][2] = {};
  const int nt = K >> 6;

#define GSTAGE(buf, k0)                                                                   \
  {                                                                                       \
    _Pragma("unroll")                                                                     \
    for (int p = 0; p < 4; ++p) {                                                         \
      const int row = p * 32 + srow;                                                      \
      const int sw = (kc ^ (row & 7)) * 8;                                                \
      GLOAD_LDS16(&A[(size_t)(m0 + row) * K + (k0) + sw], &lA[buf][row * 64 + kc * 8]);   \
    }                                                                                     \
    _Pragma("unroll")                                                                     \
    for (int p = 0; p < 2; ++p) {                                                         \
      const int row = p * 32 + srow;                                                      \
      const int sw = (kc ^ (row & 7)) * 8;                                                \
      GLOAD_LDS16(&Bt[(size_t)(n0 + row) * K + (k0) + sw], &lB[buf][row * 64 + kc * 8]);  \
    }                                                                                     \
  }
  GSTAGE(0, 0);
  asm volatile("s_waitcnt vmcnt(0)" ::: "memory");
  __syncthreads();
  int cur = 0;
  for (int t = 0; t < nt; ++t) {
    if (t + 1 < nt) GSTAGE(cur ^ 1, (t + 1) << 6);
    #pragma unroll
    for (int ks = 0; ks < 64; ks += 32) {
      bf16x8 af[4], bfr[2];
      const int kch = (ks >> 3) + g;
      #pragma unroll
      for (int mi = 0; mi < 4; ++mi) {
        const int row = wr * 64 + mi * 16 + r16;
        af[mi] = *(const bf16x8*)&lA[cur][row * 64 + (kch ^ (row & 7)) * 8];
      }
      #pragma unroll
      for (int ni = 0; ni < 2; ++ni) {
        const int row = wc * 32 + ni * 16 + r16;
        bfr[ni] = *(const bf16x8*)&lB[cur][row * 64 + (kch ^ (row & 7)) * 8];
      }
      #pragma unroll
      for (int mi = 0; mi < 4; ++mi)
        #pragma unroll
        for (int ni = 0; ni < 2; ++ni)
          acc[mi][ni] = __builtin_amdgcn_mfma_f32_16x16x32_bf16(af[mi], bfr[ni], acc[mi][ni], 0, 0, 0);
    }
    asm volatile("s_waitcnt vmcnt(0)" ::: "memory");
    __syncthreads();
    cur ^= 1;
  }
  #pragma unroll
  for (int mi = 0; mi < 4; ++mi) {
    const int r0 = m0 + wr * 64 + mi * 16 + g * 4;
    #pragma unroll
    for (int ni = 0; ni < 2; ++ni) {
      const int c = n0 + wc * 32 + ni * 16 + r16;
      #pragma unroll
      for (int j = 0; j < 4; ++j)
        C[(size_t)(r0 + j) * N + c] = acc[mi][ni][j];
    }
  }
#undef GSTAGE
}

// ---- flash attention (R12/R14-proven): triangle-paired, swapped-QK softmax,
// KVBLK=64, K/V LDS dbuf via global_load_lds (linear dest + pre-swizzled
// src); ONE barrier per tile; kf/vf hoisted per tile, shared by both sides;
// in-lane softmax with fast_exp2; deferred-max (T13).
__global__ __launch_bounds__(256) void attn_kernel(const __bf16* __restrict__ Q,
                                                   const __bf16* __restrict__ Kb,
                                                   const __bf16* __restrict__ Vt,
                                                   __bf16* __restrict__ Y) {
  __shared__ __align__(16) __bf16 lK[2][64 * 64];   // [kv][d], swizzled
  __shared__ __align__(16) __bf16 lV[2][64 * 64];   // [d][kv], swizzled
  __shared__ __align__(16) __bf16 pP[4][16 * 64];   // per-wave [q][kv], swizzled
  const int tid = threadIdx.x;
  const int lane = tid & 63, wave = tid >> 6;
  const int r16 = lane & 15, g = lane >> 4;
  // bijective XCD swizzle (T1): 512 blocks, 8 XCDs -> 64 contiguous logical
  // ids per XCD so blocks sharing (b,kvh)'s K/V co-locate in one L2.
  const int logical = (blockIdx.x & 7) * 64 + (blockIdx.x >> 3);
  const int i = logical & 15;        // pair index: q-tiles {i, 31-i}
  const int bh = logical >> 4;
  const int b = bh >> 4, h = bh & 15;
  const int kvh = h >> 2;  // GQA rep = 4
  const __bf16* Qp = Q + ((size_t)b * NH_ + h) * T_ * HD_;
  const __bf16* Kp = Kb + ((size_t)b * NKV_ + kvh) * T_ * HD_;
  const __bf16* Vp = Vt + ((size_t)b * NKV_ + kvh) * HD_ * T_;
  const int qtile[2] = { i, 31 - i };
  const int srow = tid >> 3, kc = tid & 7;          // staging: 8x16B chunks/row

#define ASTAGE(buf, kv0_)                                                                  \
  {                                                                                        \
    _Pragma("unroll")                                                                      \
    for (int p = 0; p < 2; ++p) {                                                          \
      const int row = p * 32 + srow;                                                       \
      const int sw = (kc ^ (row & 7)) * 8;                                                 \
      GLOAD_LDS16(&Kp[(size_t)((kv0_) + row) * HD_ + sw], &lK[buf][row * 64 + kc * 8]);    \
      GLOAD_LDS16(&Vp[(size_t)row * T_ + (kv0_) + sw], &lV[buf][row * 64 + kc * 8]);       \
    }                                                                                      \
  }

  // Q fragments; pre-scaled by 1/8*log2e in gemm_qkv epilogue.
  bf16x8 qf[2][2];
  #pragma unroll
  for (int sd = 0; sd < 2; ++sd)
    #pragma unroll
    for (int c = 0; c < 2; ++c)
      qf[sd][c] = *(const bf16x8*)&Qp[(size_t)(qtile[sd] * 64 + wave * 16 + r16) * HD_ + (c * 4 + g) * 8];

  f32x4 o[2][4] = {};
  float mS[2], lS[2];
  #pragma unroll
  for (int sd = 0; sd < 2; ++sd) { mS[sd] = -__builtin_inff(); lS[sd] = 0.0f; }

  // softmax + P-write for one side (lane owns full row q=qw+r16 of S^T)
  auto sm_side = [&](f32x4 (&s)[4], int sd) {
    // in-lane 16->1 max, max3-shaped triples (T17)
    float t0 = fmaxf(fmaxf(s[0][0], s[0][1]), s[0][2]);
    float t1 = fmaxf(fmaxf(s[0][3], s[1][0]), s[1][1]);
    float t2 = fmaxf(fmaxf(s[1][2], s[1][3]), s[2][0]);
    float t3 = fmaxf(fmaxf(s[2][1], s[2][2]), s[2][3]);
    float t4 = fmaxf(fmaxf(s[3][0], s[3][1]), s[3][2]);
    float pm = fmaxf(fmaxf(t0, t1), t2);
    pm = fmaxf(pm, fmaxf(t3, t4));
    pm = fmaxf(pm, s[3][3]);
    pm = fmaxf(pm, __shfl_xor(pm, 16));
    pm = fmaxf(pm, __shfl_xor(pm, 32));
    const bool upd = pm > mS[sd] + 8.0f;   // deferred-max (T13)
    const float nm = upd ? pm : mS[sd];
    const float sc = fast_exp2(mS[sd] - nm);   // ==1.0 exactly when !upd
    mS[sd] = nm;
    lS[sd] *= sc;
    if (__any(upd)) {  // redistribute sc from q=r16 layout to (g,j) layout
      #pragma unroll
      for (int j = 0; j < 4; ++j) {
        const float scj = __shfl(sc, g * 4 + j);
        #pragma unroll
        for (int nf = 0; nf < 4; ++nf) o[sd][nf][j] *= scj;
      }
    }
    // P = exp2(S-m): write each pb chunk ASAP, reduce rs after.
    float rs = 0.0f;
    #pragma unroll
    for (int ni = 0; ni < 4; ++ni) {
      bf16x4 pb;
      #pragma unroll
      for (int j = 0; j < 4; ++j) {
        const float pv = fast_exp2(s[ni][j] - mS[sd]);
        rs += pv;
        pb[j] = (__bf16)pv;
      }
      const int ch = 2 * ni + (g >> 1);    // row q=r16, kv-chunk, half g&1
      *(bf16x4*)&pP[wave][r16 * 64 + ((ch ^ (r16 & 7)) * 8) + (g & 1) * 4] = pb;
    }
    rs += __shfl_xor(rs, 16);
    rs += __shfl_xor(rs, 32);
    lS[sd] += rs;
  };

  const int ntiles = 32 - i;         // KV tiles needed by side B (q-tile 31-i)
  ASTAGE(0, 0);
  asm volatile("s_waitcnt vmcnt(0)" ::: "memory");
  __syncthreads();
  int cur = 0;

  for (int t = 0; t < ntiles; ++t) {
    const int kv0 = t << 6;
    if (t + 1 < ntiles) ASTAGE(cur ^ 1, kv0 + 64);  // next tile under compute

    // ---- hoisted K/V fragment reads: once per tile, shared by both sides ----
    bf16x8 kf[2][4], vf[2][4];
    #pragma unroll
    for (int c = 0; c < 2; ++c)
      #pragma unroll
      for (int ni = 0; ni < 4; ++ni) {
        const int row = ni * 16 + r16;
        const int sw = ((c * 4 + g) ^ (row & 7)) * 8;
        kf[c][ni] = *(const bf16x8*)&lK[cur][row * 64 + sw];
        vf[c][ni] = *(const bf16x8*)&lV[cur][row * 64 + sw];
      }

    #pragma unroll
    for (int sd = 0; sd < 2; ++sd) {
      if (sd == 0 && t > i) continue;       // side A inactive past its diagonal
      const int qw = qtile[sd] * 64 + wave * 16;

      // ---- QK^T swapped: s[ni][j] = S[kv0+ni*16+g*4+j][qw+r16] ----
      f32x4 s[4] = {};
      #pragma unroll
      for (int c = 0; c < 2; ++c)
        #pragma unroll
        for (int ni = 0; ni < 4; ++ni)
          s[ni] = __builtin_amdgcn_mfma_f32_16x16x32_bf16(kf[c][ni], qf[sd][c], s[ni], 0, 0, 0);

      // ---- causal mask (diagonal tile of this side only) ----
      if (t == ((sd == 0) ? i : (ntiles - 1))) {
        #pragma unroll
        for (int ni = 0; ni < 4; ++ni)
          #pragma unroll
          for (int j = 0; j < 4; ++j)
            if (kv0 + ni * 16 + g * 4 + j > qw + r16) s[ni][j] = -__builtin_inff();
      }

      sm_side(s, sd);
      asm volatile("s_waitcnt lgkmcnt(0)" ::: "memory");  // P writes drained

      // ---- PV: O += P * V^T, 8 MFMAs (vf from registers) ----
      #pragma unroll
      for (int c = 0; c < 2; ++c) {
        const bf16x8 pf = *(const bf16x8*)&pP[wave][r16 * 64 + (((c * 4 + g) ^ (r16 & 7)) * 8)];
        #pragma unroll
        for (int nf = 0; nf < 4; ++nf)
          o[sd][nf] = __builtin_amdgcn_mfma_f32_16x16x32_bf16(pf, vf[c][nf], o[sd][nf], 0, 0, 0);
      }
    }

    asm volatile("s_waitcnt vmcnt(0)" ::: "memory");  // next-tile loads landed
    __syncthreads();
    cur ^= 1;
  }

  // ---- epilogue -> Y[b][t][h][d] bf16 (both sides); l via shfl ----
  #pragma unroll
  for (int sd = 0; sd < 2; ++sd) {
    const int qw = qtile[sd] * 64 + wave * 16;
    #pragma unroll
    for (int j = 0; j < 4; ++j) {
      const float lq = __shfl(lS[sd], g * 4 + j);
      const float inv = 1.0f / lq;
      const int tq = qw + g * 4 + j;
      #pragma unroll
      for (int nf = 0; nf < 4; ++nf) {
        const int d = nf * 16 + r16;
        Y[(((size_t)b * T_ + tq) * NH_ + h) * HD_ + d] = (__bf16)(o[sd][nf][j] * inv);
      }
    }
  }
#undef ASTAGE
}

extern "C" void kernel_launch(void* const* d_in, const int* in_sizes, int n_in,
                              void* d_out, int out_size, void* d_ws, size_t ws_size,
                              hipStream_t stream) {
  const float* x = (const float*)d_in[0];
  const float* Wqkv = (const float*)d_in[1];
  const float* Wproj = (const float*)d_in[2];
  float* out = (float*)d_out;

  char* ws = (char*)d_ws;
  size_t off = 0;
  auto alloc = [&](size_t bytes) {
    char* p = ws + off;
    off += (bytes + 255) & ~(size_t)255;
    return p;
  };
  __bf16* xb     = (__bf16*)alloc((size_t)M_ * C_ * 2);          // 8 MB
  __bf16* wqkvT  = (__bf16*)alloc((size_t)NQKV_ * C_ * 2);       // 3 MB
  __bf16* wprojT = (__bf16*)alloc((size_t)C_ * C_ * 2);          // 2 MB
  float*  cosT   = (float*)alloc((size_t)T_ * 32 * 4);
  float*  sinT   = (float*)alloc((size_t)T_ * 32 * 4);
  __bf16* Qb     = (__bf16*)alloc((size_t)B_ * NH_ * T_ * HD_ * 2);
  __bf16* Kb     = (__bf16*)alloc((size_t)B_ * NKV_ * T_ * HD_ * 2);
  __bf16* Vt     = (__bf16*)alloc((size_t)B_ * NKV_ * T_ * HD_ * 2);
  __bf16* Yb     = (__bf16*)alloc((size_t)M_ * C_ * 2);          // 8 MB

  hipLaunchKernelGGL(prep_kernel, dim3(PREP_GRID), dim3(256), 0, stream,
                     x, Wqkv, Wproj, xb, wqkvT, wprojT, cosT, sinT);
  hipLaunchKernelGGL(gemm_qkv_kernel, dim3(NQKV_ / 64, M_ / 128), dim3(256), 0, stream,
                     xb, wqkvT, cosT, sinT, Qb, Kb, Vt);
  hipLaunchKernelGGL(attn_kernel, dim3(16 * B_ * NH_), dim3(256), 0, stream, Qb, Kb, Vt, Yb);
  hipLaunchKernelGGL(gemm_tn_kernel, dim3(C_ / 64, M_ / 128), dim3(256), 0, stream,
                     Yb, wprojT, out, C_, C_);
}

// Round 17
// 94.263 us; speedup vs baseline: 1.0913x; 1.0147x over previous
//
#include <hip/hip_runtime.h>
#include <hip/hip_bf16.h>

#define B_ 2
#define T_ 2048
#define C_ 1024
#define NH_ 16
#define NKV_ 4
#define HD_ 64
#define NQKV_ 1536           // (NH + 2*NKV) * HD
#define M_ 4096              // B_ * T_

typedef __attribute__((ext_vector_type(8))) __bf16 bf16x8;
typedef __attribute__((ext_vector_type(4))) __bf16 bf16x4;
typedef __attribute__((ext_vector_type(4))) float f32x4;
typedef __attribute__((ext_vector_type(4))) unsigned int u32x4;

// raw v_exp_f32 (D = 2^S0): 1 instruction, ~1 ulp — plenty for bf16 outputs.
__device__ __forceinline__ float fast_exp2(float x) { return __builtin_amdgcn_exp2f(x); }

#define GLOAD_LDS16(gptr, lptr)                                                        \
  __builtin_amdgcn_global_load_lds(                                                    \
      (const __attribute__((address_space(1))) unsigned int*)(gptr),                   \
      (__attribute__((address_space(3))) unsigned int*)(lptr), 16, 0, 0)

// T1 bijective XCD swizzle for a grid of nwg blocks (nwg % 8 == 0): each XCD
// gets a contiguous chunk of logical ids -> shared A/B panels co-locate in
// one L2 instead of being fetched into all 8.
__device__ __forceinline__ int xcd_swizzle(int lid, int nwg) {
  return (lid & 7) * (nwg >> 3) + (lid >> 3);
}

// ---- shared transpose-tile body: in [K][N] fp32 -> out [N][K] bf16 ----
__device__ __forceinline__ void transpose_tile_body(const float* __restrict__ in,
                                                    __bf16* __restrict__ out,
                                                    int K, int N, int n0, int k0,
                                                    __bf16 (*tile)[72], int tid) {
  const int tr = tid >> 4, tc4 = (tid & 15) << 2;
  #pragma unroll
  for (int p = 0; p < 4; ++p) {
    const int k = k0 + p * 16 + tr;
    const float4 v = *(const float4*)&in[(size_t)k * N + n0 + tc4];
    tile[tc4 + 0][p * 16 + tr] = (__bf16)v.x;
    tile[tc4 + 1][p * 16 + tr] = (__bf16)v.y;
    tile[tc4 + 2][p * 16 + tr] = (__bf16)v.z;
    tile[tc4 + 3][p * 16 + tr] = (__bf16)v.w;
  }
  __syncthreads();
  #pragma unroll
  for (int p = 0; p < 4; ++p) {
    const int n = n0 + p * 16 + tr;
    bf16x4 o;
    o.x = tile[p * 16 + tr][tc4 + 0];
    o.y = tile[p * 16 + tr][tc4 + 1];
    o.z = tile[p * 16 + tr][tc4 + 2];
    o.w = tile[p * 16 + tr][tc4 + 3];
    *(bf16x4*)&out[(size_t)n * K + k0 + tc4] = o;
  }
}

// ---- fused prep: cast_x | T(Wqkv) | T(Wproj) | rope_table ----
#define NB_CASTX 2048
#define NB_TWQKV 384
#define NB_TWPROJ 256
#define PREP_GRID (NB_CASTX + NB_TWQKV + NB_TWPROJ + 256)
__global__ __launch_bounds__(256) void prep_kernel(const float* __restrict__ x,
                                                   const float* __restrict__ Wqkv,
                                                   const float* __restrict__ Wproj,
                                                   __bf16* __restrict__ xb,
                                                   __bf16* __restrict__ wqkvT,
                                                   __bf16* __restrict__ wprojT,
                                                   float* __restrict__ cosT,
                                                   float* __restrict__ sinT) {
  __shared__ __bf16 tile[64][72];
  const int blk = blockIdx.x, tid = threadIdx.x;
  if (blk < NB_CASTX) {                      // cast x: 8 elems/thread
    const int i = blk * 256 + tid;
    const float4 v0 = ((const float4*)x)[2 * i];
    const float4 v1 = ((const float4*)x)[2 * i + 1];
    bf16x8 o;
    o[0] = (__bf16)v0.x; o[1] = (__bf16)v0.y; o[2] = (__bf16)v0.z; o[3] = (__bf16)v0.w;
    o[4] = (__bf16)v1.x; o[5] = (__bf16)v1.y; o[6] = (__bf16)v1.z; o[7] = (__bf16)v1.w;
    ((bf16x8*)xb)[i] = o;
  } else if (blk < NB_CASTX + NB_TWQKV) {    // transpose Wqkv
    const int bx = blk - NB_CASTX;
    transpose_tile_body(Wqkv, wqkvT, C_, NQKV_, (bx % (NQKV_ / 64)) * 64,
                        (bx / (NQKV_ / 64)) * 64, tile, tid);
  } else if (blk < NB_CASTX + NB_TWQKV + NB_TWPROJ) {  // transpose Wproj
    const int bx = blk - NB_CASTX - NB_TWQKV;
    transpose_tile_body(Wproj, wprojT, C_, C_, (bx % (C_ / 64)) * 64,
                        (bx / (C_ / 64)) * 64, tile, tid);
  } else {                                   // RoPE cos/sin tables [T][32]
    const int idx = (blk - NB_CASTX - NB_TWQKV - NB_TWPROJ) * 256 + tid;
    const int t = idx >> 5, i = idx & 31;
    const float inv = powf(10000.0f, -(float)i * (1.0f / 32.0f));
    const float ang = (float)t * inv;
    cosT[idx] = cosf(ang);
    sinT[idx] = sinf(ang);
  }
}

// ---- GEMM1 with FUSED RoPE + scatter epilogue: xb[M][C] * wqkvT[N][K]^T ----
// Each 64-col tile = exactly one head. Epilogue applies RoPE to Q/K cols
// (pair (d, d^1) lives in lanes (r16, r16^1) -> one shfl_xor + fma) and
// writes Q[b][h][t][d], K[b][kvh][t][d], Vt[b][kvh][d][t] directly — no qkv
// intermediate. Q pre-scaled by 1/8*log2(e) (exp2-domain softmax).
// Grid flattened 1-D + T1 XCD swizzle (768 blocks, %8==0).
__global__ __launch_bounds__(256) void gemm_qkv_kernel(const __bf16* __restrict__ A,
                                                       const __bf16* __restrict__ Bt,
                                                       const float* __restrict__ cosT,
                                                       const float* __restrict__ sinT,
                                                       __bf16* __restrict__ Q,
                                                       __bf16* __restrict__ Kb,
                                                       __bf16* __restrict__ Vt) {
  const int N = NQKV_, K = C_;
  __shared__ __align__(16) __bf16 lA[2][128 * 64];
  __shared__ __align__(16) __bf16 lB[2][64 * 64];
  const int tid = threadIdx.x;
  const int lane = tid & 63;
  const int wave = tid >> 6;
  const int wr = wave >> 1, wc = wave & 1;
  const int NBX = NQKV_ / 64;                      // 24
  const int swz = xcd_swizzle(blockIdx.x, NBX * (M_ / 128));
  const int bx = swz % NBX, by = swz / NBX;
  const int m0 = by * 128, n0 = bx * 64;
  const int srow = tid >> 3, kc = tid & 7;
  const int r16 = lane & 15, g = lane >> 4;
  f32x4 acc[4][2] = {};
  const int nt = K >> 6;

#define GSTAGE(buf, k0)                                                                   \
  {                                                                                       \
    _Pragma("unroll")                                                                     \
    for (int p = 0; p < 4; ++p) {                                                         \
      const int row = p * 32 + srow;                                                      \
      const int sw = (kc ^ (row & 7)) * 8;                                                \
      GLOAD_LDS16(&A[(size_t)(m0 + row) * K + (k0) + sw], &lA[buf][row * 64 + kc * 8]);   \
    }                                                                                     \
    _Pragma("unroll")                                                                     \
    for (int p = 0; p < 2; ++p) {                                                         \
      const int row = p * 32 + srow;                                                      \
      const int sw = (kc ^ (row & 7)) * 8;                                                \
      GLOAD_LDS16(&Bt[(size_t)(n0 + row) * K + (k0) + sw], &lB[buf][row * 64 + kc * 8]);  \
    }                                                                                     \
  }
  GSTAGE(0, 0);
  asm volatile("s_waitcnt vmcnt(0)" ::: "memory");
  __syncthreads();
  int cur = 0;
  for (int t = 0; t < nt; ++t) {
    if (t + 1 < nt) GSTAGE(cur ^ 1, (t + 1) << 6);
    #pragma unroll
    for (int ks = 0; ks < 64; ks += 32) {
      bf16x8 af[4], bfr[2];
      const int kch = (ks >> 3) + g;
      #pragma unroll
      for (int mi = 0; mi < 4; ++mi) {
        const int row = wr * 64 + mi * 16 + r16;
        af[mi] = *(const bf16x8*)&lA[cur][row * 64 + (kch ^ (row & 7)) * 8];
      }
      #pragma unroll
      for (int ni = 0; ni < 2; ++ni) {
        const int row = wc * 32 + ni * 16 + r16;
        bfr[ni] = *(const bf16x8*)&lB[cur][row * 64 + (kch ^ (row & 7)) * 8];
      }
      #pragma unroll
      for (int mi = 0; mi < 4; ++mi)
        #pragma unroll
        for (int ni = 0; ni < 2; ++ni)
          acc[mi][ni] = __builtin_amdgcn_mfma_f32_16x16x32_bf16(af[mi], bfr[ni], acc[mi][ni], 0, 0, 0);
    }
    asm volatile("s_waitcnt vmcnt(0)" ::: "memory");
    __syncthreads();
    cur ^= 1;
  }
#undef GSTAGE
  // ---- fused epilogue ----
  const bool isV = bx >= 20;          // head tile: 0..15 Q, 16..19 K, 20..23 V
  const bool isQ = bx < 16;
  const float qs = 0.125f * 1.44269504f;
  const bool evenD = (r16 & 1) == 0;
  #pragma unroll
  for (int mi = 0; mi < 4; ++mi) {
    const int t0g = m0 + wr * 64 + mi * 16 + g * 4;  // 4 consecutive t rows
    const int b = t0g >> 11, tq0 = t0g & 2047;
    #pragma unroll
    for (int ni = 0; ni < 2; ++ni) {
      const int d = wc * 32 + ni * 16 + r16;
      if (isV) {
        const int hv = bx - 20;
        bf16x4 o4;
        #pragma unroll
        for (int j = 0; j < 4; ++j) o4[j] = (__bf16)acc[mi][ni][j];
        *(bf16x4*)&Vt[(((size_t)b * NKV_ + hv) * HD_ + d) * T_ + tq0] = o4;
      } else {
        const int ir = d >> 1;
        #pragma unroll
        for (int j = 0; j < 4; ++j) {
          const float val = acc[mi][ni][j];
          const float oth = __shfl_xor(val, 1);
          const float c = cosT[(tq0 + j) * 32 + ir];
          const float s = sinT[(tq0 + j) * 32 + ir];
          float o = evenD ? (val * c - oth * s) : (oth * s + val * c);
          if (isQ) {
            Q[(((size_t)b * NH_ + bx) * T_ + tq0 + j) * HD_ + d] = (__bf16)(o * qs);
          } else {
            Kb[(((size_t)b * NKV_ + (bx - 16)) * T_ + tq0 + j) * HD_ + d] = (__bf16)o;
          }
        }
      }
    }
  }
}

// ------- bf16 TN GEMM (generic): A[M][K] * Bt[N][K]^T -> C[M][N] fp32 -------
// Grid flattened 1-D + T1 XCD swizzle (512 blocks, %8==0).
__global__ __launch_bounds__(256) void gemm_tn_kernel(const __bf16* __restrict__ A,
                                                      const __bf16* __restrict__ Bt,
                                                      float* __restrict__ C, int N, int K,
                                                      int nbx, int nwg) {
  __shared__ __align__(16) __bf16 lA[2][128 * 64];
  __shared__ __align__(16) __bf16 lB[2][64 * 64];
  const int tid = threadIdx.x;
  const int lane = tid & 63;
  const int wave = tid >> 6;
  const int wr = wave >> 1, wc = wave & 1;
  const int swz = xcd_swizzle(blockIdx.x, nwg);
  const int m0 = (swz / nbx) * 128, n0 = (swz % nbx) * 64;
  const int srow = tid >> 3, kc = tid & 7;
  const int r16 = lane & 15, g = lane >> 4;
  f32x4 acc[4][2] = {};
  const int nt = K >> 6;

#define GSTAGE(buf, k0)                                                                   \
  {                                                                                       \
    _Pragma("unroll")                                                                     \
    for (int p = 0; p < 4; ++p) {                                                         \
      const int row = p * 32 + srow;                                                      \
      const int sw = (kc ^ (row & 7)) * 8;                                                \
      GLOAD_LDS16(&A[(size_t)(m0 + row) * K + (k0) + sw], &lA[buf][row * 64 + kc * 8]);   \
    }                                                                                     \
    _Pragma("unroll")                                                                     \
    for (int p = 0; p < 2; ++p) {                                                         \
      const int row = p * 32 + srow;                                                      \
      const int sw = (kc ^ (row & 7)) * 8;                                                \
      GLOAD_LDS16(&Bt[(size_t)(n0 + row) * K + (k0) + sw], &lB[buf][row * 64 + kc * 8]);  \
    }                                                                                     \
  }
  GSTAGE(0, 0);
  asm volatile("s_waitcnt vmcnt(0)" ::: "memory");
  __syncthreads();
  int cur = 0;
  for (int t = 0; t < nt; ++t) {
    if (t + 1 < nt) GSTAGE(cur ^ 1, (t + 1) << 6);
    #pragma unroll
    for (int ks = 0; ks < 64; ks += 32) {
      bf16x8 af[4], bfr[2];
      const int kch = (ks >> 3) + g;
      #pragma unroll
      for (int mi = 0; mi < 4; ++mi) {
        const int row = wr * 64 + mi * 16 + r16;
        af[mi] = *(const bf16x8*)&lA[cur][row * 64 + (kch ^ (row & 7)) * 8];
      }
      #pragma unroll
      for (int ni = 0; ni < 2; ++ni) {
        const int row = wc * 32 + ni * 16 + r16;
        bfr[ni] = *(const bf16x8*)&lB[cur][row * 64 + (kch ^ (row & 7)) * 8];
      }
      #pragma unroll
      for (int mi = 0; mi < 4; ++mi)
        #pragma unroll
        for (int ni = 0; ni < 2; ++ni)
          acc[mi][ni] = __builtin_amdgcn_mfma_f32_16x16x32_bf16(af[mi], bfr[ni], acc[mi][ni], 0, 0, 0);
    }
    asm volatile("s_waitcnt vmcnt(0)" ::: "memory");
    __syncthreads();
    cur ^= 1;
  }
  #pragma unroll
  for (int mi = 0; mi < 4; ++mi) {
    const int r0 = m0 + wr * 64 + mi * 16 + g * 4;
    #pragma unroll
    for (int ni = 0; ni < 2; ++ni) {
      const int c = n0 + wc * 32 + ni * 16 + r16;
      #pragma unroll
      for (int j = 0; j < 4; ++j)
        C[(size_t)(r0 + j) * N + c] = acc[mi][ni][j];
    }
  }
#undef GSTAGE
}

// ---- flash attention (R12/R14-proven): triangle-paired, swapped-QK softmax,
// KVBLK=64, K/V LDS dbuf via global_load_lds (linear dest + pre-swizzled
// src); ONE barrier per tile; kf/vf hoisted per tile, shared by both sides;
// in-lane softmax with fast_exp2; deferred-max (T13).
__global__ __launch_bounds__(256) void attn_kernel(const __bf16* __restrict__ Q,
                                                   const __bf16* __restrict__ Kb,
                                                   const __bf16* __restrict__ Vt,
                                                   __bf16* __restrict__ Y) {
  __shared__ __align__(16) __bf16 lK[2][64 * 64];   // [kv][d], swizzled
  __shared__ __align__(16) __bf16 lV[2][64 * 64];   // [d][kv], swizzled
  __shared__ __align__(16) __bf16 pP[4][16 * 64];   // per-wave [q][kv], swizzled
  const int tid = threadIdx.x;
  const int lane = tid & 63, wave = tid >> 6;
  const int r16 = lane & 15, g = lane >> 4;
  // bijective XCD swizzle (T1): 512 blocks, 8 XCDs -> 64 contiguous logical
  // ids per XCD so blocks sharing (b,kvh)'s K/V co-locate in one L2.
  const int logical = (blockIdx.x & 7) * 64 + (blockIdx.x >> 3);
  const int i = logical & 15;        // pair index: q-tiles {i, 31-i}
  const int bh = logical >> 4;
  const int b = bh >> 4, h = bh & 15;
  const int kvh = h >> 2;  // GQA rep = 4
  const __bf16* Qp = Q + ((size_t)b * NH_ + h) * T_ * HD_;
  const __bf16* Kp = Kb + ((size_t)b * NKV_ + kvh) * T_ * HD_;
  const __bf16* Vp = Vt + ((size_t)b * NKV_ + kvh) * HD_ * T_;
  const int qtile[2] = { i, 31 - i };
  const int srow = tid >> 3, kc = tid & 7;          // staging: 8x16B chunks/row

#define ASTAGE(buf, kv0_)                                                                  \
  {                                                                                        \
    _Pragma("unroll")                                                                      \
    for (int p = 0; p < 2; ++p) {                                                          \
      const int row = p * 32 + srow;                                                       \
      const int sw = (kc ^ (row & 7)) * 8;                                                 \
      GLOAD_LDS16(&Kp[(size_t)((kv0_) + row) * HD_ + sw], &lK[buf][row * 64 + kc * 8]);    \
      GLOAD_LDS16(&Vp[(size_t)row * T_ + (kv0_) + sw], &lV[buf][row * 64 + kc * 8]);       \
    }                                                                                      \
  }

  // Q fragments; pre-scaled by 1/8*log2e in gemm_qkv epilogue.
  bf16x8 qf[2][2];
  #pragma unroll
  for (int sd = 0; sd < 2; ++sd)
    #pragma unroll
    for (int c = 0; c < 2; ++c)
      qf[sd][c] = *(const bf16x8*)&Qp[(size_t)(qtile[sd] * 64 + wave * 16 + r16) * HD_ + (c * 4 + g) * 8];

  f32x4 o[2][4] = {};
  float mS[2], lS[2];
  #pragma unroll
  for (int sd = 0; sd < 2; ++sd) { mS[sd] = -__builtin_inff(); lS[sd] = 0.0f; }

  // softmax + P-write for one side (lane owns full row q=qw+r16 of S^T)
  auto sm_side = [&](f32x4 (&s)[4], int sd) {
    // in-lane 16->1 max, max3-shaped triples (T17)
    float t0 = fmaxf(fmaxf(s[0][0], s[0][1]), s[0][2]);
    float t1 = fmaxf(fmaxf(s[0][3], s[1][0]), s[1][1]);
    float t2 = fmaxf(fmaxf(s[1][2], s[1][3]), s[2][0]);
    float t3 = fmaxf(fmaxf(s[2][1], s[2][2]), s[2][3]);
    float t4 = fmaxf(fmaxf(s[3][0], s[3][1]), s[3][2]);
    float pm = fmaxf(fmaxf(t0, t1), t2);
    pm = fmaxf(pm, fmaxf(t3, t4));
    pm = fmaxf(pm, s[3][3]);
    pm = fmaxf(pm, __shfl_xor(pm, 16));
    pm = fmaxf(pm, __shfl_xor(pm, 32));
    const bool upd = pm > mS[sd] + 8.0f;   // deferred-max (T13)
    const float nm = upd ? pm : mS[sd];
    const float sc = fast_exp2(mS[sd] - nm);   // ==1.0 exactly when !upd
    mS[sd] = nm;
    lS[sd] *= sc;
    if (__any(upd)) {  // redistribute sc from q=r16 layout to (g,j) layout
      #pragma unroll
      for (int j = 0; j < 4; ++j) {
        const float scj = __shfl(sc, g * 4 + j);
        #pragma unroll
        for (int nf = 0; nf < 4; ++nf) o[sd][nf][j] *= scj;
      }
    }
    // P = exp2(S-m): write each pb chunk ASAP, reduce rs after.
    float rs = 0.0f;
    #pragma unroll
    for (int ni = 0; ni < 4; ++ni) {
      bf16x4 pb;
      #pragma unroll
      for (int j = 0; j < 4; ++j) {
        const float pv = fast_exp2(s[ni][j] - mS[sd]);
        rs += pv;
        pb[j] = (__bf16)pv;
      }
      const int ch = 2 * ni + (g >> 1);    // row q=r16, kv-chunk, half g&1
      *(bf16x4*)&pP[wave][r16 * 64 + ((ch ^ (r16 & 7)) * 8) + (g & 1) * 4] = pb;
    }
    rs += __shfl_xor(rs, 16);
    rs += __shfl_xor(rs, 32);
    lS[sd] += rs;
  };

  const int ntiles = 32 - i;         // KV tiles needed by side B (q-tile 31-i)
  ASTAGE(0, 0);
  asm volatile("s_waitcnt vmcnt(0)" ::: "memory");
  __syncthreads();
  int cur = 0;

  for (int t = 0; t < ntiles; ++t) {
    const int kv0 = t << 6;
    if (t + 1 < ntiles) ASTAGE(cur ^ 1, kv0 + 64);  // next tile under compute

    // ---- hoisted K/V fragment reads: once per tile, shared by both sides ----
    bf16x8 kf[2][4], vf[2][4];
    #pragma unroll
    for (int c = 0; c < 2; ++c)
      #pragma unroll
      for (int ni = 0; ni < 4; ++ni) {
        const int row = ni * 16 + r16;
        const int sw = ((c * 4 + g) ^ (row & 7)) * 8;
        kf[c][ni] = *(const bf16x8*)&lK[cur][row * 64 + sw];
        vf[c][ni] = *(const bf16x8*)&lV[cur][row * 64 + sw];
      }

    #pragma unroll
    for (int sd = 0; sd < 2; ++sd) {
      if (sd == 0 && t > i) continue;       // side A inactive past its diagonal
      const int qw = qtile[sd] * 64 + wave * 16;

      // ---- QK^T swapped: s[ni][j] = S[kv0+ni*16+g*4+j][qw+r16] ----
      f32x4 s[4] = {};
      #pragma unroll
      for (int c = 0; c < 2; ++c)
        #pragma unroll
        for (int ni = 0; ni < 4; ++ni)
          s[ni] = __builtin_amdgcn_mfma_f32_16x16x32_bf16(kf[c][ni], qf[sd][c], s[ni], 0, 0, 0);

      // ---- causal mask (diagonal tile of this side only) ----
      if (t == ((sd == 0) ? i : (ntiles - 1))) {
        #pragma unroll
        for (int ni = 0; ni < 4; ++ni)
          #pragma unroll
          for (int j = 0; j < 4; ++j)
            if (kv0 + ni * 16 + g * 4 + j > qw + r16) s[ni][j] = -__builtin_inff();
      }

      sm_side(s, sd);
      asm volatile("s_waitcnt lgkmcnt(0)" ::: "memory");  // P writes drained

      // ---- PV: O += P * V^T, 8 MFMAs (vf from registers) ----
      #pragma unroll
      for (int c = 0; c < 2; ++c) {
        const bf16x8 pf = *(const bf16x8*)&pP[wave][r16 * 64 + (((c * 4 + g) ^ (r16 & 7)) * 8)];
        #pragma unroll
        for (int nf = 0; nf < 4; ++nf)
          o[sd][nf] = __builtin_amdgcn_mfma_f32_16x16x32_bf16(pf, vf[c][nf], o[sd][nf], 0, 0, 0);
      }
    }

    asm volatile("s_waitcnt vmcnt(0)" ::: "memory");  // next-tile loads landed
    __syncthreads();
    cur ^= 1;
  }

  // ---- epilogue -> Y[b][t][h][d] bf16 (both sides); l via shfl ----
  #pragma unroll
  for (int sd = 0; sd < 2; ++sd) {
    const int qw = qtile[sd] * 64 + wave * 16;
    #pragma unroll
    for (int j = 0; j < 4; ++j) {
      const float lq = __shfl(lS[sd], g * 4 + j);
      const float inv = 1.0f / lq;
      const int tq = qw + g * 4 + j;
      #pragma unroll
      for (int nf = 0; nf < 4; ++nf) {
        const int d = nf * 16 + r16;
        Y[(((size_t)b * T_ + tq) * NH_ + h) * HD_ + d] = (__bf16)(o[sd][nf][j] * inv);
      }
    }
  }
#undef ASTAGE
}

extern "C" void kernel_launch(void* const* d_in, const int* in_sizes, int n_in,
                              void* d_out, int out_size, void* d_ws, size_t ws_size,
                              hipStream_t stream) {
  const float* x = (const float*)d_in[0];
  const float* Wqkv = (const float*)d_in[1];
  const float* Wproj = (const float*)d_in[2];
  float* out = (float*)d_out;

  char* ws = (char*)d_ws;
  size_t off = 0;
  auto alloc = [&](size_t bytes) {
    char* p = ws + off;
    off += (bytes + 255) & ~(size_t)255;
    return p;
  };
  __bf16* xb     = (__bf16*)alloc((size_t)M_ * C_ * 2);          // 8 MB
  __bf16* wqkvT  = (__bf16*)alloc((size_t)NQKV_ * C_ * 2);       // 3 MB
  __bf16* wprojT = (__bf16*)alloc((size_t)C_ * C_ * 2);          // 2 MB
  float*  cosT   = (float*)alloc((size_t)T_ * 32 * 4);
  float*  sinT   = (float*)alloc((size_t)T_ * 32 * 4);
  __bf16* Qb     = (__bf16*)alloc((size_t)B_ * NH_ * T_ * HD_ * 2);
  __bf16* Kb     = (__bf16*)alloc((size_t)B_ * NKV_ * T_ * HD_ * 2);
  __bf16* Vt     = (__bf16*)alloc((size_t)B_ * NKV_ * T_ * HD_ * 2);
  __bf16* Yb     = (__bf16*)alloc((size_t)M_ * C_ * 2);          // 8 MB

  hipLaunchKernelGGL(prep_kernel, dim3(PREP_GRID), dim3(256), 0, stream,
                     x, Wqkv, Wproj, xb, wqkvT, wprojT, cosT, sinT);
  hipLaunchKernelGGL(gemm_qkv_kernel, dim3((NQKV_ / 64) * (M_ / 128)), dim3(256), 0, stream,
                     xb, wqkvT, cosT, sinT, Qb, Kb, Vt);
  hipLaunchKernelGGL(attn_kernel, dim3(16 * B_ * NH_), dim3(256), 0, stream, Qb, Kb, Vt, Yb);
  hipLaunchKernelGGL(gemm_tn_kernel, dim3((C_ / 64) * (M_ / 128)), dim3(256), 0, stream,
                     Yb, wprojT, out, C_, C_, C_ / 64, (C_ / 64) * (M_ / 128));
}

// Round 18
// 93.661 us; speedup vs baseline: 1.0983x; 1.0064x over previous
//
#include <hip/hip_runtime.h>
#include <hip/hip_bf16.h>

#define B_ 2
#define T_ 2048
#define C_ 1024
#define NH_ 16
#define NKV_ 4
#define HD_ 64
#define NQKV_ 1536           // (NH + 2*NKV) * HD
#define M_ 4096              // B_ * T_

typedef __attribute__((ext_vector_type(8))) __bf16 bf16x8;
typedef __attribute__((ext_vector_type(4))) __bf16 bf16x4;
typedef __attribute__((ext_vector_type(4))) float f32x4;
typedef __attribute__((ext_vector_type(4))) unsigned int u32x4;

// raw v_exp_f32 (D = 2^S0): 1 instruction, ~1 ulp — plenty for bf16 outputs.
__device__ __forceinline__ float fast_exp2(float x) { return __builtin_amdgcn_exp2f(x); }

#define GLOAD_LDS16(gptr, lptr)                                                        \
  __builtin_amdgcn_global_load_lds(                                                    \
      (const __attribute__((address_space(1))) unsigned int*)(gptr),                   \
      (__attribute__((address_space(3))) unsigned int*)(lptr), 16, 0, 0)

// T1 bijective XCD swizzle for a grid of nwg blocks (nwg % 8 == 0): each XCD
// gets a contiguous chunk of logical ids -> shared A/B panels co-locate in
// one L2 instead of being fetched into all 8.
__device__ __forceinline__ int xcd_swizzle(int lid, int nwg) {
  return (lid & 7) * (nwg >> 3) + (lid >> 3);
}

// ---- shared transpose-tile body: in [K][N] fp32 -> out [N][K] bf16 ----
__device__ __forceinline__ void transpose_tile_body(const float* __restrict__ in,
                                                    __bf16* __restrict__ out,
                                                    int K, int N, int n0, int k0,
                                                    __bf16 (*tile)[72], int tid) {
  const int tr = tid >> 4, tc4 = (tid & 15) << 2;
  #pragma unroll
  for (int p = 0; p < 4; ++p) {
    const int k = k0 + p * 16 + tr;
    const float4 v = *(const float4*)&in[(size_t)k * N + n0 + tc4];
    tile[tc4 + 0][p * 16 + tr] = (__bf16)v.x;
    tile[tc4 + 1][p * 16 + tr] = (__bf16)v.y;
    tile[tc4 + 2][p * 16 + tr] = (__bf16)v.z;
    tile[tc4 + 3][p * 16 + tr] = (__bf16)v.w;
  }
  __syncthreads();
  #pragma unroll
  for (int p = 0; p < 4; ++p) {
    const int n = n0 + p * 16 + tr;
    bf16x4 o;
    o.x = tile[p * 16 + tr][tc4 + 0];
    o.y = tile[p * 16 + tr][tc4 + 1];
    o.z = tile[p * 16 + tr][tc4 + 2];
    o.w = tile[p * 16 + tr][tc4 + 3];
    *(bf16x4*)&out[(size_t)n * K + k0 + tc4] = o;
  }
}

// ---- fused prep: cast_x | T(Wqkv) | T(Wproj) | rope_table ----
#define NB_CASTX 2048
#define NB_TWQKV 384
#define NB_TWPROJ 256
#define PREP_GRID (NB_CASTX + NB_TWQKV + NB_TWPROJ + 256)
__global__ __launch_bounds__(256) void prep_kernel(const float* __restrict__ x,
                                                   const float* __restrict__ Wqkv,
                                                   const float* __restrict__ Wproj,
                                                   __bf16* __restrict__ xb,
                                                   __bf16* __restrict__ wqkvT,
                                                   __bf16* __restrict__ wprojT,
                                                   float* __restrict__ cosT,
                                                   float* __restrict__ sinT) {
  __shared__ __bf16 tile[64][72];
  const int blk = blockIdx.x, tid = threadIdx.x;
  if (blk < NB_CASTX) {                      // cast x: 8 elems/thread
    const int i = blk * 256 + tid;
    const float4 v0 = ((const float4*)x)[2 * i];
    const float4 v1 = ((const float4*)x)[2 * i + 1];
    bf16x8 o;
    o[0] = (__bf16)v0.x; o[1] = (__bf16)v0.y; o[2] = (__bf16)v0.z; o[3] = (__bf16)v0.w;
    o[4] = (__bf16)v1.x; o[5] = (__bf16)v1.y; o[6] = (__bf16)v1.z; o[7] = (__bf16)v1.w;
    ((bf16x8*)xb)[i] = o;
  } else if (blk < NB_CASTX + NB_TWQKV) {    // transpose Wqkv
    const int bx = blk - NB_CASTX;
    transpose_tile_body(Wqkv, wqkvT, C_, NQKV_, (bx % (NQKV_ / 64)) * 64,
                        (bx / (NQKV_ / 64)) * 64, tile, tid);
  } else if (blk < NB_CASTX + NB_TWQKV + NB_TWPROJ) {  // transpose Wproj
    const int bx = blk - NB_CASTX - NB_TWQKV;
    transpose_tile_body(Wproj, wprojT, C_, C_, (bx % (C_ / 64)) * 64,
                        (bx / (C_ / 64)) * 64, tile, tid);
  } else {                                   // RoPE cos/sin tables [T][32]
    const int idx = (blk - NB_CASTX - NB_TWQKV - NB_TWPROJ) * 256 + tid;
    const int t = idx >> 5, i = idx & 31;
    const float inv = powf(10000.0f, -(float)i * (1.0f / 32.0f));
    const float ang = (float)t * inv;
    cosT[idx] = cosf(ang);
    sinT[idx] = sinf(ang);
  }
}

// ---- GEMM1 with FUSED RoPE + scatter epilogue: xb[M][C] * wqkvT[N][K]^T ----
// Each 64-col tile = exactly one head. Epilogue applies RoPE to Q/K cols
// (pair (d, d^1) lives in lanes (r16, r16^1) -> one shfl_xor + fma) and
// writes Q[b][h][t][d], K[b][kvh][t][d], Vt[b][kvh][d][t] directly — no qkv
// intermediate. Q pre-scaled by 1/8*log2(e) (exp2-domain softmax).
// Grid flattened 1-D + T1 XCD swizzle (768 blocks, %8==0).
__global__ __launch_bounds__(256) void gemm_qkv_kernel(const __bf16* __restrict__ A,
                                                       const __bf16* __restrict__ Bt,
                                                       const float* __restrict__ cosT,
                                                       const float* __restrict__ sinT,
                                                       __bf16* __restrict__ Q,
                                                       __bf16* __restrict__ Kb,
                                                       __bf16* __restrict__ Vt) {
  const int N = NQKV_, K = C_;
  __shared__ __align__(16) __bf16 lA[2][128 * 64];
  __shared__ __align__(16) __bf16 lB[2][64 * 64];
  const int tid = threadIdx.x;
  const int lane = tid & 63;
  const int wave = tid >> 6;
  const int wr = wave >> 1, wc = wave & 1;
  const int NBX = NQKV_ / 64;                      // 24
  const int swz = xcd_swizzle(blockIdx.x, NBX * (M_ / 128));
  const int bx = swz % NBX, by = swz / NBX;
  const int m0 = by * 128, n0 = bx * 64;
  const int srow = tid >> 3, kc = tid & 7;
  const int r16 = lane & 15, g = lane >> 4;
  f32x4 acc[4][2] = {};
  const int nt = K >> 6;

#define GSTAGE(buf, k0)                                                                   \
  {                                                                                       \
    _Pragma("unroll")                                                                     \
    for (int p = 0; p < 4; ++p) {                                                         \
      const int row = p * 32 + srow;                                                      \
      const int sw = (kc ^ (row & 7)) * 8;                                                \
      GLOAD_LDS16(&A[(size_t)(m0 + row) * K + (k0) + sw], &lA[buf][row * 64 + kc * 8]);   \
    }                                                                                     \
    _Pragma("unroll")                                                                     \
    for (int p = 0; p < 2; ++p) {                                                         \
      const int row = p * 32 + srow;                                                      \
      const int sw = (kc ^ (row & 7)) * 8;                                                \
      GLOAD_LDS16(&Bt[(size_t)(n0 + row) * K + (k0) + sw], &lB[buf][row * 64 + kc * 8]);  \
    }                                                                                     \
  }
  GSTAGE(0, 0);
  asm volatile("s_waitcnt vmcnt(0)" ::: "memory");
  __syncthreads();
  int cur = 0;
  for (int t = 0; t < nt; ++t) {
    if (t + 1 < nt) GSTAGE(cur ^ 1, (t + 1) << 6);
    #pragma unroll
    for (int ks = 0; ks < 64; ks += 32) {
      bf16x8 af[4], bfr[2];
      const int kch = (ks >> 3) + g;
      #pragma unroll
      for (int mi = 0; mi < 4; ++mi) {
        const int row = wr * 64 + mi * 16 + r16;
        af[mi] = *(const bf16x8*)&lA[cur][row * 64 + (kch ^ (row & 7)) * 8];
      }
      #pragma unroll
      for (int ni = 0; ni < 2; ++ni) {
        const int row = wc * 32 + ni * 16 + r16;
        bfr[ni] = *(const bf16x8*)&lB[cur][row * 64 + (kch ^ (row & 7)) * 8];
      }
      #pragma unroll
      for (int mi = 0; mi < 4; ++mi)
        #pragma unroll
        for (int ni = 0; ni < 2; ++ni)
          acc[mi][ni] = __builtin_amdgcn_mfma_f32_16x16x32_bf16(af[mi], bfr[ni], acc[mi][ni], 0, 0, 0);
    }
    asm volatile("s_waitcnt vmcnt(0)" ::: "memory");
    __syncthreads();
    cur ^= 1;
  }
#undef GSTAGE
  // ---- fused epilogue ----
  const bool isV = bx >= 20;          // head tile: 0..15 Q, 16..19 K, 20..23 V
  const bool isQ = bx < 16;
  const float qs = 0.125f * 1.44269504f;
  const bool evenD = (r16 & 1) == 0;
  #pragma unroll
  for (int mi = 0; mi < 4; ++mi) {
    const int t0g = m0 + wr * 64 + mi * 16 + g * 4;  // 4 consecutive t rows
    const int b = t0g >> 11, tq0 = t0g & 2047;
    #pragma unroll
    for (int ni = 0; ni < 2; ++ni) {
      const int d = wc * 32 + ni * 16 + r16;
      if (isV) {
        const int hv = bx - 20;
        bf16x4 o4;
        #pragma unroll
        for (int j = 0; j < 4; ++j) o4[j] = (__bf16)acc[mi][ni][j];
        *(bf16x4*)&Vt[(((size_t)b * NKV_ + hv) * HD_ + d) * T_ + tq0] = o4;
      } else {
        const int ir = d >> 1;
        #pragma unroll
        for (int j = 0; j < 4; ++j) {
          const float val = acc[mi][ni][j];
          const float oth = __shfl_xor(val, 1);
          const float c = cosT[(tq0 + j) * 32 + ir];
          const float s = sinT[(tq0 + j) * 32 + ir];
          float o = evenD ? (val * c - oth * s) : (oth * s + val * c);
          if (isQ) {
            Q[(((size_t)b * NH_ + bx) * T_ + tq0 + j) * HD_ + d] = (__bf16)(o * qs);
          } else {
            Kb[(((size_t)b * NKV_ + (bx - 16)) * T_ + tq0 + j) * HD_ + d] = (__bf16)o;
          }
        }
      }
    }
  }
}

// ------- bf16 TN GEMM (generic): A[M][K] * Bt[N][K]^T -> C[M][N] fp32 -------
// Grid flattened 1-D + T1 XCD swizzle (512 blocks, %8==0).
__global__ __launch_bounds__(256) void gemm_tn_kernel(const __bf16* __restrict__ A,
                                                      const __bf16* __restrict__ Bt,
                                                      float* __restrict__ C, int N, int K,
                                                      int nbx, int nwg) {
  __shared__ __align__(16) __bf16 lA[2][128 * 64];
  __shared__ __align__(16) __bf16 lB[2][64 * 64];
  const int tid = threadIdx.x;
  const int lane = tid & 63;
  const int wave = tid >> 6;
  const int wr = wave >> 1, wc = wave & 1;
  const int swz = xcd_swizzle(blockIdx.x, nwg);
  const int m0 = (swz / nbx) * 128, n0 = (swz % nbx) * 64;
  const int srow = tid >> 3, kc = tid & 7;
  const int r16 = lane & 15, g = lane >> 4;
  f32x4 acc[4][2] = {};
  const int nt = K >> 6;

#define GSTAGE(buf, k0)                                                                   \
  {                                                                                       \
    _Pragma("unroll")                                                                     \
    for (int p = 0; p < 4; ++p) {                                                         \
      const int row = p * 32 + srow;                                                      \
      const int sw = (kc ^ (row & 7)) * 8;                                                \
      GLOAD_LDS16(&A[(size_t)(m0 + row) * K + (k0) + sw], &lA[buf][row * 64 + kc * 8]);   \
    }                                                                                     \
    _Pragma("unroll")                                                                     \
    for (int p = 0; p < 2; ++p) {                                                         \
      const int row = p * 32 + srow;                                                      \
      const int sw = (kc ^ (row & 7)) * 8;                                                \
      GLOAD_LDS16(&Bt[(size_t)(n0 + row) * K + (k0) + sw], &lB[buf][row * 64 + kc * 8]);  \
    }                                                                                     \
  }
  GSTAGE(0, 0);
  asm volatile("s_waitcnt vmcnt(0)" ::: "memory");
  __syncthreads();
  int cur = 0;
  for (int t = 0; t < nt; ++t) {
    if (t + 1 < nt) GSTAGE(cur ^ 1, (t + 1) << 6);
    #pragma unroll
    for (int ks = 0; ks < 64; ks += 32) {
      bf16x8 af[4], bfr[2];
      const int kch = (ks >> 3) + g;
      #pragma unroll
      for (int mi = 0; mi < 4; ++mi) {
        const int row = wr * 64 + mi * 16 + r16;
        af[mi] = *(const bf16x8*)&lA[cur][row * 64 + (kch ^ (row & 7)) * 8];
      }
      #pragma unroll
      for (int ni = 0; ni < 2; ++ni) {
        const int row = wc * 32 + ni * 16 + r16;
        bfr[ni] = *(const bf16x8*)&lB[cur][row * 64 + (kch ^ (row & 7)) * 8];
      }
      #pragma unroll
      for (int mi = 0; mi < 4; ++mi)
        #pragma unroll
        for (int ni = 0; ni < 2; ++ni)
          acc[mi][ni] = __builtin_amdgcn_mfma_f32_16x16x32_bf16(af[mi], bfr[ni], acc[mi][ni], 0, 0, 0);
    }
    asm volatile("s_waitcnt vmcnt(0)" ::: "memory");
    __syncthreads();
    cur ^= 1;
  }
  #pragma unroll
  for (int mi = 0; mi < 4; ++mi) {
    const int r0 = m0 + wr * 64 + mi * 16 + g * 4;
    #pragma unroll
    for (int ni = 0; ni < 2; ++ni) {
      const int c = n0 + wc * 32 + ni * 16 + r16;
      #pragma unroll
      for (int j = 0; j < 4; ++j)
        C[(size_t)(r0 + j) * N + c] = acc[mi][ni][j];
    }
  }
#undef GSTAGE
}

// ---- flash attention (R12/R14-proven): triangle-paired, swapped-QK softmax,
// KVBLK=64, K/V LDS dbuf via global_load_lds (linear dest + pre-swizzled
// src); ONE barrier per tile; kf/vf hoisted per tile, shared by both sides;
// in-lane softmax with fast_exp2; deferred-max (T13).
// R18: the s_waitcnt lgkmcnt(0) between P-writes and PV reads is replaced by
// a compile-time sched_barrier(0): DS ops from one wave complete IN ORDER,
// so same-wave LDS RAW is coherent without a drain; the compiler still waits
// (counted lgkmcnt) before the pf read's use. Removes a ~50-100cy serial
// bubble per tile-side at zero runtime cost.
__global__ __launch_bounds__(256) void attn_kernel(const __bf16* __restrict__ Q,
                                                   const __bf16* __restrict__ Kb,
                                                   const __bf16* __restrict__ Vt,
                                                   __bf16* __restrict__ Y) {
  __shared__ __align__(16) __bf16 lK[2][64 * 64];   // [kv][d], swizzled
  __shared__ __align__(16) __bf16 lV[2][64 * 64];   // [d][kv], swizzled
  __shared__ __align__(16) __bf16 pP[4][16 * 64];   // per-wave [q][kv], swizzled
  const int tid = threadIdx.x;
  const int lane = tid & 63, wave = tid >> 6;
  const int r16 = lane & 15, g = lane >> 4;
  // bijective XCD swizzle (T1): 512 blocks, 8 XCDs -> 64 contiguous logical
  // ids per XCD so blocks sharing (b,kvh)'s K/V co-locate in one L2.
  const int logical = (blockIdx.x & 7) * 64 + (blockIdx.x >> 3);
  const int i = logical & 15;        // pair index: q-tiles {i, 31-i}
  const int bh = logical >> 4;
  const int b = bh >> 4, h = bh & 15;
  const int kvh = h >> 2;  // GQA rep = 4
  const __bf16* Qp = Q + ((size_t)b * NH_ + h) * T_ * HD_;
  const __bf16* Kp = Kb + ((size_t)b * NKV_ + kvh) * T_ * HD_;
  const __bf16* Vp = Vt + ((size_t)b * NKV_ + kvh) * HD_ * T_;
  const int qtile[2] = { i, 31 - i };
  const int srow = tid >> 3, kc = tid & 7;          // staging: 8x16B chunks/row

#define ASTAGE(buf, kv0_)                                                                  \
  {                                                                                        \
    _Pragma("unroll")                                                                      \
    for (int p = 0; p < 2; ++p) {                                                          \
      const int row = p * 32 + srow;                                                       \
      const int sw = (kc ^ (row & 7)) * 8;                                                 \
      GLOAD_LDS16(&Kp[(size_t)((kv0_) + row) * HD_ + sw], &lK[buf][row * 64 + kc * 8]);    \
      GLOAD_LDS16(&Vp[(size_t)row * T_ + (kv0_) + sw], &lV[buf][row * 64 + kc * 8]);       \
    }                                                                                      \
  }

  // Q fragments; pre-scaled by 1/8*log2e in gemm_qkv epilogue.
  bf16x8 qf[2][2];
  #pragma unroll
  for (int sd = 0; sd < 2; ++sd)
    #pragma unroll
    for (int c = 0; c < 2; ++c)
      qf[sd][c] = *(const bf16x8*)&Qp[(size_t)(qtile[sd] * 64 + wave * 16 + r16) * HD_ + (c * 4 + g) * 8];

  f32x4 o[2][4] = {};
  float mS[2], lS[2];
  #pragma unroll
  for (int sd = 0; sd < 2; ++sd) { mS[sd] = -__builtin_inff(); lS[sd] = 0.0f; }

  // softmax + P-write for one side (lane owns full row q=qw+r16 of S^T)
  auto sm_side = [&](f32x4 (&s)[4], int sd) {
    // in-lane 16->1 max, max3-shaped triples (T17)
    float t0 = fmaxf(fmaxf(s[0][0], s[0][1]), s[0][2]);
    float t1 = fmaxf(fmaxf(s[0][3], s[1][0]), s[1][1]);
    float t2 = fmaxf(fmaxf(s[1][2], s[1][3]), s[2][0]);
    float t3 = fmaxf(fmaxf(s[2][1], s[2][2]), s[2][3]);
    float t4 = fmaxf(fmaxf(s[3][0], s[3][1]), s[3][2]);
    float pm = fmaxf(fmaxf(t0, t1), t2);
    pm = fmaxf(pm, fmaxf(t3, t4));
    pm = fmaxf(pm, s[3][3]);
    pm = fmaxf(pm, __shfl_xor(pm, 16));
    pm = fmaxf(pm, __shfl_xor(pm, 32));
    const bool upd = pm > mS[sd] + 8.0f;   // deferred-max (T13)
    const float nm = upd ? pm : mS[sd];
    const float sc = fast_exp2(mS[sd] - nm);   // ==1.0 exactly when !upd
    mS[sd] = nm;
    lS[sd] *= sc;
    if (__any(upd)) {  // redistribute sc from q=r16 layout to (g,j) layout
      #pragma unroll
      for (int j = 0; j < 4; ++j) {
        const float scj = __shfl(sc, g * 4 + j);
        #pragma unroll
        for (int nf = 0; nf < 4; ++nf) o[sd][nf][j] *= scj;
      }
    }
    // P = exp2(S-m): write each pb chunk ASAP, reduce rs after.
    float rs = 0.0f;
    #pragma unroll
    for (int ni = 0; ni < 4; ++ni) {
      bf16x4 pb;
      #pragma unroll
      for (int j = 0; j < 4; ++j) {
        const float pv = fast_exp2(s[ni][j] - mS[sd]);
        rs += pv;
        pb[j] = (__bf16)pv;
      }
      const int ch = 2 * ni + (g >> 1);    // row q=r16, kv-chunk, half g&1
      *(bf16x4*)&pP[wave][r16 * 64 + ((ch ^ (r16 & 7)) * 8) + (g & 1) * 4] = pb;
    }
    rs += __shfl_xor(rs, 16);
    rs += __shfl_xor(rs, 32);
    lS[sd] += rs;
  };

  const int ntiles = 32 - i;         // KV tiles needed by side B (q-tile 31-i)
  ASTAGE(0, 0);
  asm volatile("s_waitcnt vmcnt(0)" ::: "memory");
  __syncthreads();
  int cur = 0;

  for (int t = 0; t < ntiles; ++t) {
    const int kv0 = t << 6;
    if (t + 1 < ntiles) ASTAGE(cur ^ 1, kv0 + 64);  // next tile under compute

    // ---- hoisted K/V fragment reads: once per tile, shared by both sides ----
    bf16x8 kf[2][4], vf[2][4];
    #pragma unroll
    for (int c = 0; c < 2; ++c)
      #pragma unroll
      for (int ni = 0; ni < 4; ++ni) {
        const int row = ni * 16 + r16;
        const int sw = ((c * 4 + g) ^ (row & 7)) * 8;
        kf[c][ni] = *(const bf16x8*)&lK[cur][row * 64 + sw];
        vf[c][ni] = *(const bf16x8*)&lV[cur][row * 64 + sw];
      }

    #pragma unroll
    for (int sd = 0; sd < 2; ++sd) {
      if (sd == 0 && t > i) continue;       // side A inactive past its diagonal
      const int qw = qtile[sd] * 64 + wave * 16;

      // ---- QK^T swapped: s[ni][j] = S[kv0+ni*16+g*4+j][qw+r16] ----
      f32x4 s[4] = {};
      #pragma unroll
      for (int c = 0; c < 2; ++c)
        #pragma unroll
        for (int ni = 0; ni < 4; ++ni)
          s[ni] = __builtin_amdgcn_mfma_f32_16x16x32_bf16(kf[c][ni], qf[sd][c], s[ni], 0, 0, 0);

      // ---- causal mask (diagonal tile of this side only) ----
      if (t == ((sd == 0) ? i : (ntiles - 1))) {
        #pragma unroll
        for (int ni = 0; ni < 4; ++ni)
          #pragma unroll
          for (int j = 0; j < 4; ++j)
            if (kv0 + ni * 16 + g * 4 + j > qw + r16) s[ni][j] = -__builtin_inff();
      }

      sm_side(s, sd);
      // No runtime DS drain: same-wave DS ops complete in order (LDS RAW
      // coherent); sched_barrier(0) pins compiler ordering at zero cost.
      __builtin_amdgcn_sched_barrier(0);

      // ---- PV: O += P * V^T, 8 MFMAs (vf from registers) ----
      #pragma unroll
      for (int c = 0; c < 2; ++c) {
        const bf16x8 pf = *(const bf16x8*)&pP[wave][r16 * 64 + (((c * 4 + g) ^ (r16 & 7)) * 8)];
        #pragma unroll
        for (int nf = 0; nf < 4; ++nf)
          o[sd][nf] = __builtin_amdgcn_mfma_f32_16x16x32_bf16(pf, vf[c][nf], o[sd][nf], 0, 0, 0);
      }
    }

    asm volatile("s_waitcnt vmcnt(0)" ::: "memory");  // next-tile loads landed
    __syncthreads();
    cur ^= 1;
  }

  // ---- epilogue -> Y[b][t][h][d] bf16 (both sides); l via shfl ----
  #pragma unroll
  for (int sd = 0; sd < 2; ++sd) {
    const int qw = qtile[sd] * 64 + wave * 16;
    #pragma unroll
    for (int j = 0; j < 4; ++j) {
      const float lq = __shfl(lS[sd], g * 4 + j);
      const float inv = 1.0f / lq;
      const int tq = qw + g * 4 + j;
      #pragma unroll
      for (int nf = 0; nf < 4; ++nf) {
        const int d = nf * 16 + r16;
        Y[(((size_t)b * T_ + tq) * NH_ + h) * HD_ + d] = (__bf16)(o[sd][nf][j] * inv);
      }
    }
  }
#undef ASTAGE
}

extern "C" void kernel_launch(void* const* d_in, const int* in_sizes, int n_in,
                              void* d_out, int out_size, void* d_ws, size_t ws_size,
                              hipStream_t stream) {
  const float* x = (const float*)d_in[0];
  const float* Wqkv = (const float*)d_in[1];
  const float* Wproj = (const float*)d_in[2];
  float* out = (float*)d_out;

  char* ws = (char*)d_ws;
  size_t off = 0;
  auto alloc = [&](size_t bytes) {
    char* p = ws + off;
    off += (bytes + 255) & ~(size_t)255;
    return p;
  };
  __bf16* xb     = (__bf16*)alloc((size_t)M_ * C_ * 2);          // 8 MB
  __bf16* wqkvT  = (__bf16*)alloc((size_t)NQKV_ * C_ * 2);       // 3 MB
  __bf16* wprojT = (__bf16*)alloc((size_t)C_ * C_ * 2);          // 2 MB
  float*  cosT   = (float*)alloc((size_t)T_ * 32 * 4);
  float*  sinT   = (float*)alloc((size_t)T_ * 32 * 4);
  __bf16* Qb     = (__bf16*)alloc((size_t)B_ * NH_ * T_ * HD_ * 2);
  __bf16* Kb     = (__bf16*)alloc((size_t)B_ * NKV_ * T_ * HD_ * 2);
  __bf16* Vt     = (__bf16*)alloc((size_t)B_ * NKV_ * T_ * HD_ * 2);
  __bf16* Yb     = (__bf16*)alloc((size_t)M_ * C_ * 2);          // 8 MB

  hipLaunchKernelGGL(prep_kernel, dim3(PREP_GRID), dim3(256), 0, stream,
                     x, Wqkv, Wproj, xb, wqkvT, wprojT, cosT, sinT);
  hipLaunchKernelGGL(gemm_qkv_kernel, dim3((NQKV_ / 64) * (M_ / 128)), dim3(256), 0, stream,
                     xb, wqkvT, cosT, sinT, Qb, Kb, Vt);
  hipLaunchKernelGGL(attn_kernel, dim3(16 * B_ * NH_), dim3(256), 0, stream, Qb, Kb, Vt, Yb);
  hipLaunchKernelGGL(gemm_tn_kernel, dim3((C_ / 64) * (M_ / 128)), dim3(256), 0, stream,
                     Yb, wprojT, out, C_, C_, C_ / 64, (C_ / 64) * (M_ / 128));
}